// Round 6
// baseline (353.507 us; speedup 1.0000x reference)
//
#include <hip/hip_runtime.h>

#define B_   2
#define S_   2048
#define H_   8
#define D_   64
#define DM_  1024
#define PJ_  512          // H_*D_ = projection width
#define NT_  32           // S_/64 i-tiles
#define NTRI 528          // NT_*(NT_+1)/2 lower-triangular 64-tiles
#define NCHK2 40          // split-j chunks per (b,hh) over 128-row i-blocks

typedef short bf16x8 __attribute__((ext_vector_type(8)));
typedef float f32x4 __attribute__((ext_vector_type(4)));

__device__ __forceinline__ float bf2f(unsigned int u) {
  return __uint_as_float(u << 16);
}
__device__ __forceinline__ unsigned short f2bf(float f) {
  unsigned int u = __float_as_uint(f);
  u += 0x7fffu + ((u >> 16) & 1u);           // round-to-nearest-even
  return (unsigned short)(u >> 16);
}
// packed f32x2 -> bf16x2 (RNE), gfx950 has no builtin (T12) — inline asm
__device__ __forceinline__ unsigned int cvtpk_bf16(float lo, float hi) {
  unsigned int r;
  asm("v_cvt_pk_bf16_f32 %0, %1, %2" : "=v"(r) : "v"(lo), "v"(hi));
  return r;
}
__device__ __forceinline__ bf16x8 u4_to_bf(uint4 v) {
  union { uint4 a; bf16x8 b; } u; u.a = v; return u.b;
}

// async global->LDS DMA, 16 B/lane; LDS dest = wave-uniform base + lane*16
__device__ __forceinline__ void glds16(const unsigned short* g, unsigned short* l) {
  __builtin_amdgcn_global_load_lds(
      (const __attribute__((address_space(1))) void*)g,
      (__attribute__((address_space(3))) void*)l, 16, 0, 0);
}

// ---------------------------------------------------------------------------
// f32 -> bf16 conversion (12 jobs; wr stays f32 and is read directly).
// ---------------------------------------------------------------------------
struct CvtJobs {
  const float*    src[12];
  unsigned short* dst[12];
  int             n4[12];
};

__global__ __launch_bounds__(256) void cvt_many(CvtJobs J) {
  const int j = blockIdx.y;
  const int i = blockIdx.x * 256 + threadIdx.x;
  if (i >= J.n4[j]) return;
  const float4 v = ((const float4*)J.src[j])[i];
  ushort4 o;
  o.x = f2bf(v.x); o.y = f2bf(v.y); o.z = f2bf(v.z); o.w = f2bf(v.w);
  ((ushort4*)J.dst[j])[i] = o;
}

// ---------------------------------------------------------------------------
// 128x128-tile MFMA GEMM with global_load_lds staging (m97 ladder step).
// ---------------------------------------------------------------------------
__device__ __forceinline__
void gemm128_glds(const unsigned short* __restrict__ A, int m0,
                  const unsigned short* __restrict__ Wb,
                  unsigned short* __restrict__ Cb, int ldc, int KD,
                  unsigned short* As, unsigned short* Bs)
{
  const int tid = threadIdx.x;
  const int wv = tid >> 6, lane = tid & 63;
  const int r15 = lane & 15, quad = lane >> 4;
  const int wm = (wv >> 1) * 64, wn = (wv & 1) * 64;
  f32x4 acc[4][4];
#pragma unroll
  for (int i = 0; i < 4; ++i)
#pragma unroll
    for (int j = 0; j < 4; ++j) acc[i][j] = (f32x4){0.f, 0.f, 0.f, 0.f};

  const int srow = wv * 16 + (lane >> 2);
  const int scol = ((lane & 3) ^ ((lane >> 3) & 3)) * 8;   // xor-swizzled source col
  const unsigned short* gaA0 = A + (size_t)(m0 + srow) * KD + scol;
  const unsigned short* gaA1 = gaA0 + (size_t)64 * KD;
  const unsigned short* gaB0 = Wb + (size_t)srow * KD + scol;
  const unsigned short* gaB1 = gaB0 + (size_t)64 * KD;
  unsigned short* ldsA0 = As + wv * 512;
  unsigned short* ldsA1 = As + 2048 + wv * 512;
  unsigned short* ldsB0 = Bs + wv * 512;
  unsigned short* ldsB1 = Bs + 2048 + wv * 512;
  const int rxor = (r15 >> 1) & 3;                         // read-side xor

  for (int kk = 0; kk < KD; kk += 32) {
    __syncthreads();
    glds16(gaA0 + kk, ldsA0);
    glds16(gaA1 + kk, ldsA1);
    glds16(gaB0 + kk, ldsB0);
    glds16(gaB1 + kk, ldsB1);
    __syncthreads();     // drains vmcnt for the DMA
    bf16x8 af[4], bf[4];
#pragma unroll
    for (int i = 0; i < 4; ++i)
      af[i] = *(const bf16x8*)(As + (wm + i * 16 + r15) * 32 + ((quad ^ rxor) << 3));
#pragma unroll
    for (int j = 0; j < 4; ++j)
      bf[j] = *(const bf16x8*)(Bs + (wn + j * 16 + r15) * 32 + ((quad ^ rxor) << 3));
#pragma unroll
    for (int i = 0; i < 4; ++i)
#pragma unroll
      for (int j = 0; j < 4; ++j)
        acc[i][j] = __builtin_amdgcn_mfma_f32_16x16x32_bf16(af[i], bf[j], acc[i][j], 0, 0, 0);
  }
#pragma unroll
  for (int i = 0; i < 4; ++i)
#pragma unroll
    for (int r = 0; r < 4; ++r) {
      unsigned short* cp = Cb + (size_t)(wm + i * 16 + quad * 4 + r) * ldc + wn + r15;
#pragma unroll
      for (int j = 0; j < 4; ++j) cp[j * 16] = f2bf(acc[i][j][r]);
    }
}

// 8 projection GEMMs in one launch. grid (32, 32)
__global__ __launch_bounds__(256)
void proj_tiled(const unsigned short* __restrict__ XB,
                const unsigned short* __restrict__ SYB,
                const unsigned short* __restrict__ Wcat,
                unsigned short* __restrict__ Qbase,
                unsigned short* __restrict__ SV)
{
  __shared__ unsigned short As[128 * 32];
  __shared__ unsigned short Bs[128 * 32];
  const int m0 = blockIdx.x * 128;
  const int ny = blockIdx.y;
  const size_t NB = (size_t)B_ * S_ * PJ_;
  const unsigned short* A;
  const unsigned short* Wb;
  unsigned short* Cb;
  if (ny < 28) {
    const int n0 = ny * 128;
    A  = XB;
    Wb = Wcat + (size_t)n0 * DM_;
    Cb = Qbase + (size_t)(n0 >> 9) * NB + (size_t)m0 * PJ_ + (n0 & 511);
  } else {
    const int n0 = (ny - 28) * 128;
    A  = SYB;
    Wb = Wcat + (size_t)7 * PJ_ * DM_ + (size_t)n0 * DM_;
    Cb = SV + (size_t)m0 * PJ_ + n0;
  }
  gemm128_glds(A, m0, Wb, Cb, PJ_, DM_, As, Bs);
}

// ---------------------------------------------------------------------------
// Output projections: 128m x 64n tiles (512 blocks). grid (32, 16).
// ---------------------------------------------------------------------------
__global__ __launch_bounds__(256)
void out_tiled(const unsigned short* __restrict__ Asa,
               const unsigned short* __restrict__ Ara,
               const unsigned short* __restrict__ WOSA,
               const unsigned short* __restrict__ WORA,
               float* __restrict__ Out)
{
  __shared__ unsigned short As[128 * 40];
  __shared__ unsigned short Bs[64 * 40];
  const int m0 = blockIdx.x * 128;
  const int ny = blockIdx.y;
  const int n0 = (ny & 7) * 64;
  const unsigned short* A  = (ny < 8) ? Asa : Ara;
  const unsigned short* Wb = ((ny < 8) ? WOSA : WORA) + (size_t)n0 * PJ_;
  float* Cb = Out + (size_t)m0 * DM_ + ((ny < 8) ? 0 : 512) + n0;

  const int tid = threadIdx.x;
  const int wv = tid >> 6, lane = tid & 63;
  const int r15 = lane & 15, quad = lane >> 4;
  const int wm = wv * 32;
  f32x4 acc[2][4];
#pragma unroll
  for (int i = 0; i < 2; ++i)
#pragma unroll
    for (int j = 0; j < 4; ++j) acc[i][j] = (f32x4){0.f, 0.f, 0.f, 0.f};

  const int arow = tid >> 1, ac = (tid & 1) * 16;
  const int brow = tid >> 2, bc = (tid & 3) * 8;
  const unsigned short* ga = A + (size_t)(m0 + arow) * PJ_ + ac;
  const unsigned short* gb = Wb + (size_t)brow * PJ_ + bc;
  unsigned short* la = As + arow * 40 + ac;
  unsigned short* lb = Bs + brow * 40 + bc;

  for (int kk = 0; kk < PJ_; kk += 32) {
    __syncthreads();
    const uint4 a0 = *(const uint4*)(ga + kk);
    const uint4 a1 = *(const uint4*)(ga + kk + 8);
    const uint4 b0 = *(const uint4*)(gb + kk);
    *(uint4*)la       = a0;
    *(uint4*)(la + 8) = a1;
    *(uint4*)lb       = b0;
    __syncthreads();
    bf16x8 af[2], bf[4];
#pragma unroll
    for (int i = 0; i < 2; ++i)
      af[i] = *(const bf16x8*)(As + (wm + i * 16 + r15) * 40 + quad * 8);
#pragma unroll
    for (int j = 0; j < 4; ++j)
      bf[j] = *(const bf16x8*)(Bs + (j * 16 + r15) * 40 + quad * 8);
#pragma unroll
    for (int i = 0; i < 2; ++i)
#pragma unroll
      for (int j = 0; j < 4; ++j)
        acc[i][j] = __builtin_amdgcn_mfma_f32_16x16x32_bf16(af[i], bf[j], acc[i][j], 0, 0, 0);
  }
#pragma unroll
  for (int i = 0; i < 2; ++i)
#pragma unroll
    for (int r = 0; r < 4; ++r) {
      float* cp = Cb + (size_t)(wm + i * 16 + quad * 4 + r) * DM_ + r15;
#pragma unroll
      for (int j = 0; j < 4; ++j) cp[j * 16] = acc[i][j][r];
    }
}

// ---------------------------------------------------------------------------
// rel materialization (tri-128 LDS GEMM), FUSED with vectorized RoPE.
// Tiles stored in B-frag-sigma order so flash_part feeds them DIRECTLY into
// MFMA as the second operand (arp-as-MFMA):
//   flat tile index = sub*1024 + k0*512 + lane*8 + jj  holds
//   rel[i' = sub*16 + (lane&15)][j = ((k0<<1)|(jj>>2))*16 + (lane>>4)*4 + (jj&3)]
// grid (136, 16).
// ---------------------------------------------------------------------------
__global__ __launch_bounds__(256)
void rel_rope(const unsigned short* __restrict__ QRg, const unsigned short* __restrict__ KRg,
              unsigned short* __restrict__ RelCF,
              unsigned short* __restrict__ Qp, unsigned short* __restrict__ Kp,
              unsigned short* __restrict__ QAp, unsigned short* __restrict__ KAp,
              const float* __restrict__ fcp, const float* __restrict__ fsp)
{
  __shared__ unsigned short As[128 * 72];
  __shared__ unsigned short Bs[128 * 72];
  const int t = blockIdx.x;
  int I = 0;
  while ((I + 1) * (I + 2) / 2 <= t) ++I;
  const int J = t - I * (I + 1) / 2;
  const int rr = blockIdx.y & 7, b = blockIdx.y >> 3;
  const int tid = threadIdx.x;
  const int wv = tid >> 6, lane = tid & 63;
  const int r15 = lane & 15, quad = lane >> 4;

  const int srow = tid >> 1, c32 = (tid & 1) * 32;
  const unsigned short* ga = QRg + (size_t)(b * S_ + I * 128 + srow) * PJ_ + rr * 64 + c32;
  const unsigned short* gb = KRg + (size_t)(b * S_ + J * 128 + srow) * PJ_ + rr * 64 + c32;
  unsigned short* la = As + srow * 72 + c32;
  unsigned short* lb = Bs + srow * 72 + c32;
#pragma unroll
  for (int q = 0; q < 4; ++q) {
    *(uint4*)(la + q * 8) = *(const uint4*)(ga + q * 8);
    *(uint4*)(lb + q * 8) = *(const uint4*)(gb + q * 8);
  }
  __syncthreads();

  const int wm = (wv >> 1) * 64, wn = (wv & 1) * 64;
  const int it64 = 2 * I + (wv >> 1), jt64 = 2 * J + (wv & 1);
  if (jt64 <= it64) {
    f32x4 acc[4][4];           // acc[a][b]: a = j-16-block, b = i-16-block
#pragma unroll
    for (int a = 0; a < 4; ++a)
#pragma unroll
      for (int bq = 0; bq < 4; ++bq) acc[a][bq] = (f32x4){0.f, 0.f, 0.f, 0.f};
#pragma unroll
    for (int k0 = 0; k0 < 2; ++k0) {
      bf16x8 af[4], bf[4];
#pragma unroll
      for (int i = 0; i < 4; ++i)
        af[i] = *(const bf16x8*)(As + (wm + i * 16 + r15) * 72 + quad * 8 + k0 * 32);
#pragma unroll
      for (int j = 0; j < 4; ++j)
        bf[j] = *(const bf16x8*)(Bs + (wn + j * 16 + r15) * 72 + quad * 8 + k0 * 32);
#pragma unroll
      for (int a = 0; a < 4; ++a)
#pragma unroll
        for (int bq = 0; bq < 4; ++bq)
          acc[a][bq] = __builtin_amdgcn_mfma_f32_16x16x32_bf16(bf[a], af[bq], acc[a][bq], 0, 0, 0);
    }
    unsigned short* out = RelCF + ((size_t)(b * 8 + rr) * NTRI + (size_t)it64 * (it64 + 1) / 2 + jt64) * 4096;
#pragma unroll
    for (int bq = 0; bq < 4; ++bq) {
      unsigned short tmp[16];
#pragma unroll
      for (int a = 0; a < 4; ++a)
#pragma unroll
        for (int r = 0; r < 4; ++r)
          tmp[a * 4 + r] = f2bf(acc[a][bq][r] * 0.125f);
      unsigned short* op = out + (size_t)bq * 1024 + (size_t)lane * 8;   // k0=0 half
      *(uint4*)op         = *(const uint4*)tmp;
      *(uint4*)(op + 512) = *(const uint4*)(tmp + 8);                    // k0=1 half
    }
  }

  // ---- fused RoPE (all threads): 2 uint4 slices of {Q,K,QA,KA} each ----
  // per-tensor uint4 count = NB/8 = 262144 = 2^18; total = 4*2^18 = 1048576.
  const int bid = (int)blockIdx.y * 136 + (int)blockIdx.x;
  const int gt = bid * 256 + tid;
#pragma unroll
  for (int k = 0; k < 2; ++k) {
    const int i = gt * 2 + k;
    if (i >= 4 * 262144) continue;
    const int tn = i >> 18;
    const int r2 = i & 262143;
    unsigned short* P = (tn == 0) ? Qp : (tn == 1) ? Kp : (tn == 2) ? QAp : KAp;
    const int b2 = r2 >> 17;                  // 131072 uint4 per batch
    const int s2 = (r2 >> 6) & 2047;          // 64 uint4 per 512-wide row
    const int c8 = (r2 & 63) * 8;             // column offset (elements)
    const int ci0 = (c8 & 63) >> 1;           // first rotary index of 4 pairs
    const size_t off2 = ((size_t)(b2 * S_ + s2)) * PJ_ + c8;
    uint4 v = *(const uint4*)(P + off2);
    unsigned int u[4] = {v.x, v.y, v.z, v.w};
    unsigned int o[4];
#pragma unroll
    for (int q = 0; q < 4; ++q) {
      const float xr = __uint_as_float(u[q] << 16);
      const float xi = __uint_as_float(u[q] & 0xffff0000u);
      const float cs = fcp[s2 * 32 + ci0 + q];
      const float sn = fsp[s2 * 32 + ci0 + q];
      const unsigned short lo = f2bf(xr * cs - xi * sn);
      const unsigned short hi = f2bf(xr * sn + xi * cs);
      o[q] = (unsigned int)lo | ((unsigned int)hi << 16);
    }
    uint4 ov; ov.x = o[0]; ov.y = o[1]; ov.z = o[2]; ov.w = o[3];
    *(uint4*)(P + off2) = ov;
  }
}

// ---------------------------------------------------------------------------
// Split-j flash partial pass — r20 on the r19 structure:
//  * K NEVER goes through LDS: the K B-fragment is a per-lane contiguous 16B
//    global load (row jtt*64+n*16+r15, col quad*8+k0*32) — the 8KB K tile is
//    L1/L2-hot (256KB per (b,h)).  Deletes the K load->store->barrier round
//    trip, halves LDS (73728 -> 36864 B) and its bank conflicts.
//  * fully-masked tiles skipped (wave-uniform jtt > it_wave early-out).
//  * s_setprio(1) around the MFMA clusters (T5; 2 independent blocks/CU
//    provide the phase diversity it needs).
//  * NO launch-bounds min-waves arg (r1/r18 lesson: it clamps to the 64-VGPR
//    tier and spills catastrophically).
// grid (40, 16, 2). Partials per chunk: Po bf16 128x64, l f32 128, arp f32 128x8.
// ---------------------------------------------------------------------------
__global__ __launch_bounds__(512)
void flash_part(const unsigned short* __restrict__ Qsa, const unsigned short* __restrict__ Ksa,
                const unsigned short* __restrict__ Vsa,
                const unsigned short* __restrict__ Qra, const unsigned short* __restrict__ Kra,
                const unsigned short* __restrict__ SVra,
                const unsigned short* __restrict__ RelCF,
                unsigned short* __restrict__ PoP, float* __restrict__ lP,
                float* __restrict__ arpP)
{
  __shared__ unsigned short Vt[2][2][64][72];   // [buf][tile][d][kslot]
  const int x = NCHK2 - 1 - (int)blockIdx.x;    // big chunks dispatch first
  int a, c;
  if (x < 4)       { a = x;                 c = 0; }
  else if (x < 12) { a = 4 + ((x - 4) >> 1);  c = (x - 4) & 1; }
  else if (x < 24) { a = 8 + (x - 12) / 3;    c = (x - 12) % 3; }
  else             { a = 12 + ((x - 24) >> 2); c = (x - 24) & 3; }
  const int j0 = c * 8;
  const int jendF = 2 * a + 2;
  const int jend = (j0 + 8 < jendF) ? (j0 + 8) : jendF;   // always even
  const bool ra = (blockIdx.y >= 8);
  const int h = blockIdx.y & 7;
  const int b = blockIdx.z;
  const int chunkId = (b * 16 + (int)blockIdx.y) * NCHK2 + x;
  const unsigned short* Qg = ra ? Qra : Qsa;
  const unsigned short* Kg = ra ? Kra : Ksa;
  const unsigned short* Vg = ra ? SVra : Vsa;
  const int tid = threadIdx.x;
  const int wv = tid >> 6, lane = tid & 63;
  const int r15 = lane & 15, quad = lane >> 4;
  const size_t bh = (size_t)b * S_ * PJ_ + (size_t)h * D_;
  const size_t relStride = (size_t)NTRI * 4096;
  const int it_wave = 2 * a + (wv >> 2);        // wave-uniform
  const int gi = a * 128 + wv * 16 + r15;       // lane's global i-row

  // V staging address (per-thread constant); 512 threads: one uint4 per tile
  const unsigned short* vgp = Vg + bh + (size_t)lane * PJ_ + wv * 8;  // V row=lane, d=wv*8..+7
  // sigma^-1: k-slot for this thread's staged V column (j = lane)
  const int kcol = ((lane >> 2) & 3) * 8 + ((lane >> 4) & 1) * 4 + (lane & 3) + (lane >> 5) * 32;
  // K direct-global per-lane fragment base (row offset r15, col quad*8)
  const unsigned short* kfb = Kg + bh + (size_t)r15 * PJ_ + quad * 8;

  // Q fragments in registers (layout: row=r15, k=quad*8+j — serves as B-frag)
  const unsigned short* qp = Qg + bh + (size_t)gi * PJ_ + quad * 8;
  const bf16x8 aq0 = *(const bf16x8*)qp;
  const bf16x8 aq1 = *(const bf16x8*)(qp + 32);

  const bf16x8 ones = (bf16x8)(short)0x3F80;   // bf16 1.0 splat (B-frag for l)

  f32x4 o_acc[4];
  f32x4 l_acc = (f32x4){0.f, 0.f, 0.f, 0.f};
  f32x4 accR[8];                               // arp MFMA accumulators (ra only)
#pragma unroll
  for (int n = 0; n < 4; ++n) o_acc[n] = (f32x4){0.f, 0.f, 0.f, 0.f};
#pragma unroll
  for (int rr = 0; rr < 8; ++rr) accR[rr] = (f32x4){0.f, 0.f, 0.f, 0.f};
  // B-frag-sigma rel tile base for this wave's 64-tile row (it_wave)
  const size_t relTileBase = (size_t)(b * 8) * NTRI * 4096
                           + (size_t)(it_wave * (it_wave + 1)) / 2 * 4096
                           + (size_t)(wv & 3) * 1024 + (size_t)lane * 8;

  // one j-tile's QK/softmax/l/arp/PV; V from LDS slot VtT, K direct from L2
  auto TILE = [&](int jtt, const unsigned short (*VtT)[72]) {
    if (jtt > it_wave) return;                 // fully-masked tile: exact 0
    const unsigned short* rtBase = RelCF + relTileBase + (size_t)jtt * 4096;
    uint4 pre[8];
    if (ra) {
      const unsigned short* rt = rtBase;
#pragma unroll
      for (int q = 0; q < 4; ++q) {
        pre[2 * q]     = *(const uint4*)rt;
        pre[2 * q + 1] = *(const uint4*)(rt + 512);
        rt += relStride;
      }
    }
    // QK^T, SWAPPED operands: lane row i=gi, j = jtt*64 + n*16 + quad*4 + r
    const unsigned short* kt = kfb + (size_t)jtt * 64 * PJ_;
    f32x4 s[4];
#pragma unroll
    for (int n = 0; n < 4; ++n) s[n] = (f32x4){0.f, 0.f, 0.f, 0.f};
    __builtin_amdgcn_s_setprio(1);
#pragma unroll
    for (int k0 = 0; k0 < 2; ++k0) {
      const bf16x8 bq = k0 ? aq1 : aq0;
#pragma unroll
      for (int n = 0; n < 4; ++n) {
        const bf16x8 kf = *(const bf16x8*)(kt + (size_t)(n * 16) * PJ_ + k0 * 32);
        s[n] = __builtin_amdgcn_mfma_f32_16x16x32_bf16(kf, bq, s[n], 0, 0, 0);
      }
    }
    __builtin_amdgcn_s_setprio(0);
    // fixed-shift softmax: exp(s*0.125-4) = exp2(fma(s, log2e/8, -4log2e))
    if (jtt == it_wave) {   // diagonal tile
#pragma unroll
      for (int n = 0; n < 4; ++n)
#pragma unroll
        for (int r = 0; r < 4; ++r) {
          const bool ok = (jtt * 64 + n * 16 + quad * 4 + r <= gi);
          s[n][r] = ok ? exp2f(fmaf(s[n][r], 0.180336887f, -5.770780163f)) : 0.f;
        }
    } else {
#pragma unroll
      for (int n = 0; n < 4; ++n)
#pragma unroll
        for (int r = 0; r < 4; ++r)
          s[n][r] = exp2f(fmaf(s[n][r], 0.180336887f, -5.770780163f));
    }
    // packed P->bf16 under sigma
    uint4 w0, w1;
    w0.x = cvtpk_bf16(s[0][0], s[0][1]); w0.y = cvtpk_bf16(s[0][2], s[0][3]);
    w0.z = cvtpk_bf16(s[1][0], s[1][1]); w0.w = cvtpk_bf16(s[1][2], s[1][3]);
    w1.x = cvtpk_bf16(s[2][0], s[2][1]); w1.y = cvtpk_bf16(s[2][2], s[2][3]);
    w1.z = cvtpk_bf16(s[3][0], s[3][1]); w1.w = cvtpk_bf16(s[3][2], s[3][3]);
    const bf16x8 pa0 = u4_to_bf(w0);
    const bf16x8 pa1 = u4_to_bf(w1);
    __builtin_amdgcn_s_setprio(1);
    // l via MFMA against constant ones B-frag
    l_acc = __builtin_amdgcn_mfma_f32_16x16x32_bf16(pa0, ones, l_acc, 0, 0, 0);
    l_acc = __builtin_amdgcn_mfma_f32_16x16x32_bf16(pa1, ones, l_acc, 0, 0, 0);
    // arp MFMAs rr=0..3 (diag of D = arp)
    if (ra) {
#pragma unroll
      for (int rr = 0; rr < 4; ++rr) {
        accR[rr] = __builtin_amdgcn_mfma_f32_16x16x32_bf16(pa0, u4_to_bf(pre[2 * rr]), accR[rr], 0, 0, 0);
        accR[rr] = __builtin_amdgcn_mfma_f32_16x16x32_bf16(pa1, u4_to_bf(pre[2 * rr + 1]), accR[rr], 0, 0, 0);
      }
    }
    // PV: 8 MFMAs (Vt columns are sigma-permuted)
#pragma unroll
    for (int k0 = 0; k0 < 2; ++k0) {
      const bf16x8 pf = k0 ? pa1 : pa0;
#pragma unroll
      for (int n = 0; n < 4; ++n) {
        const bf16x8 vf = *(const bf16x8*)&VtT[n * 16 + r15][quad * 8 + k0 * 32];
        o_acc[n] = __builtin_amdgcn_mfma_f32_16x16x32_bf16(pf, vf, o_acc[n], 0, 0, 0);
      }
    }
    // arp MFMAs rr=4..7 (loads overlap PV above)
    if (ra) {
      const unsigned short* rt2 = rtBase + 4 * relStride;
#pragma unroll
      for (int rr = 4; rr < 8; ++rr) {
        const bf16x8 rb0 = *(const bf16x8*)rt2;
        const bf16x8 rb1 = *(const bf16x8*)(rt2 + 512);
        accR[rr] = __builtin_amdgcn_mfma_f32_16x16x32_bf16(pa0, rb0, accR[rr], 0, 0, 0);
        accR[rr] = __builtin_amdgcn_mfma_f32_16x16x32_bf16(pa1, rb1, accR[rr], 0, 0, 0);
        rt2 += relStride;
      }
    }
    __builtin_amdgcn_s_setprio(0);
  };

  // prologue: load V for round (j0, j0+1), store to buf 0
  uint4 va0, va1;
  {
    const size_t jb0 = (size_t)j0 * 64 * PJ_;
    const size_t jb1 = (size_t)(j0 + 1) * 64 * PJ_;
    va0 = *(const uint4*)(vgp + jb0);
    va1 = *(const uint4*)(vgp + jb1);
  }
  int p = 0;
  {
    unsigned short t8[8];
    *(uint4*)t8 = va0;
#pragma unroll
    for (int m = 0; m < 8; ++m) Vt[0][0][wv * 8 + m][kcol] = t8[m];
    *(uint4*)t8 = va1;
#pragma unroll
    for (int m = 0; m < 8; ++m) Vt[0][1][wv * 8 + m][kcol] = t8[m];
  }
  __syncthreads();

  for (int jt = j0; jt < jend; jt += 2) {
    const bool more = (jt + 2 < jend);
    if (more) {   // issue next round's V loads (2 tiles of compute to hide)
      const size_t jb0 = (size_t)(jt + 2) * 64 * PJ_;
      const size_t jb1 = (size_t)(jt + 3) * 64 * PJ_;
      va0 = *(const uint4*)(vgp + jb0);
      va1 = *(const uint4*)(vgp + jb1);
    }
    TILE(jt,     Vt[p][0]);
    TILE(jt + 1, Vt[p][1]);
    if (more) {
      const int q = p ^ 1;
      unsigned short t8[8];
      *(uint4*)t8 = va0;
#pragma unroll
      for (int m = 0; m < 8; ++m) Vt[q][0][wv * 8 + m][kcol] = t8[m];
      *(uint4*)t8 = va1;
#pragma unroll
      for (int m = 0; m < 8; ++m) Vt[q][1][wv * 8 + m][kcol] = t8[m];
      __syncthreads();
      p = q;
    }
  }
  // ---- write partials (chunk: Po 128x64, l 128, arp 128x8) ----
  unsigned short* po = PoP + (size_t)chunkId * 8192;
#pragma unroll
  for (int n = 0; n < 4; ++n)
#pragma unroll
    for (int r = 0; r < 4; ++r)
      po[(wv * 16 + quad * 4 + r) * 64 + n * 16 + r15] = f2bf(o_acc[n][r]);
  if (r15 == 0) {
#pragma unroll
    for (int r = 0; r < 4; ++r)
      lP[(size_t)chunkId * 128 + wv * 16 + quad * 4 + r] = l_acc[r];
  }
  // arp: diagonal lanes (quad == r15>>2) hold the full j-sum in comp r15&3
  if (ra && quad == (r15 >> 2)) {
    const int d3 = r15 & 3;
    float* ap = arpP + (size_t)chunkId * 1024 + (size_t)(wv * 16 + r15) * 8;
#pragma unroll
    for (int rr = 0; rr < 8; ++rr) {
      const f32x4 a4 = accR[rr];
      const float v = (d3 == 0) ? a4[0] : (d3 == 1) ? a4[1] : (d3 == 2) ? a4[2] : a4[3];
      ap[rr] = v;
    }
  }
}

// ---------------------------------------------------------------------------
// Merge split-j partials (pure sums) + wr (f32) epilogue. grid (32, 16, 2).
// Chunks are 128-row i-blocks; tile it -> block a = it>>1, half = it&1.
// ---------------------------------------------------------------------------
__global__ __launch_bounds__(256)
void flash_merge(const unsigned short* __restrict__ PoP, const float* __restrict__ lP,
                 const float* __restrict__ arpP, const float* __restrict__ wrF,
                 unsigned short* __restrict__ Osa, unsigned short* __restrict__ Ora)
{
  const int it = blockIdx.x;
  const int hh = blockIdx.y;
  const int b  = blockIdx.z;
  const bool ra = (hh >= 8);
  const int h = hh & 7;
  const int a  = it >> 1;
  const int half = it & 1;
  const int nc = ((2 * a + 1) >> 3) + 1;
  int cb;
  if (a < 4)       cb = a;
  else if (a < 8)  cb = 4 + 2 * (a - 4);
  else if (a < 12) cb = 12 + 3 * (a - 8);
  else             cb = 24 + 4 * (a - 12);
  const int cid0 = (b * 16 + hh) * NCHK2 + cb;
  const int tid = threadIdx.x;
  const int row = tid >> 2;            // 0..63 within this 64-row half
  const int cg  = tid & 3;
  const int prow = half * 64 + row;    // row within the 128-row chunk

  float L = 0.f;
  for (int c = 0; c < nc; ++c) L += lP[(size_t)(cid0 + c) * 128 + prow];
  const float inv = 1.f / L;

  float o[16];
#pragma unroll
  for (int k = 0; k < 16; ++k) o[k] = 0.f;
  for (int c = 0; c < nc; ++c) {
    const unsigned short* pp = PoP + (size_t)(cid0 + c) * 8192 + prow * 64 + cg * 16;
    unsigned int u[8];
    *(uint4*)u       = *(const uint4*)pp;
    *(uint4*)(u + 4) = *(const uint4*)(pp + 8);
#pragma unroll
    for (int q = 0; q < 8; ++q) {
      o[2 * q]     += __uint_as_float(u[q] << 16);
      o[2 * q + 1] += __uint_as_float(u[q] & 0xffff0000u);
    }
  }
  if (ra) {
    float A[8];
#pragma unroll
    for (int rr = 0; rr < 8; ++rr) A[rr] = 0.f;
    for (int c = 0; c < nc; ++c) {
      const float* ap = arpP + (size_t)(cid0 + c) * 1024 + (size_t)prow * 8;
#pragma unroll
      for (int rr = 0; rr < 8; ++rr) A[rr] += ap[rr];
    }
#pragma unroll
    for (int k = 0; k < 16; ++k) {
      const float* wp = wrF + ((size_t)h * 64 + cg * 16 + k) * 8;
      float ro = 0.f;
#pragma unroll
      for (int rr = 0; rr < 8; ++rr) ro += A[rr] * wp[rr];
      o[k] += ro;
    }
  }
  const size_t bh = (size_t)b * S_ * PJ_ + (size_t)h * D_;
  unsigned short* op = (ra ? Ora : Osa) + bh + (size_t)(it * 64 + row) * PJ_ + cg * 16;
#pragma unroll
  for (int k = 0; k < 16; ++k) op[k] = f2bf(o[k] * inv);
}

// ---------------------------------------------------------------------------
extern "C" void kernel_launch(void* const* d_in, const int* in_sizes, int n_in,
                              void* d_out, int out_size, void* d_ws, size_t ws_size,
                              hipStream_t stream)
{
  (void)in_sizes; (void)n_in; (void)out_size; (void)ws_size;
  const float* x    = (const float*)d_in[0];
  const float* sym  = (const float*)d_in[1];
  const float* fc   = (const float*)d_in[2];
  const float* fs   = (const float*)d_in[3];
  const float* wqsa = (const float*)d_in[4];
  const float* wksa = (const float*)d_in[5];
  const float* wvsa = (const float*)d_in[6];
  const float* wosa = (const float*)d_in[7];
  const float* wqat = (const float*)d_in[8];
  const float* wkat = (const float*)d_in[9];
  const float* wqre = (const float*)d_in[10];
  const float* wkre = (const float*)d_in[11];
  const float* wr   = (const float*)d_in[12];
  const float* wvra = (const float*)d_in[13];
  const float* wora = (const float*)d_in[14];

  unsigned short* wsb = (unsigned short*)d_ws;
  const size_t NX = (size_t)B_ * S_ * DM_;
  const size_t NB = (size_t)B_ * S_ * PJ_;
  const size_t NW = (size_t)PJ_ * DM_;
  const size_t NO = (size_t)PJ_ * PJ_;
  const size_t NR = (size_t)B_ * 8 * NTRI * 4096;
  const size_t NCH = (size_t)B_ * 16 * NCHK2;   // 1280 chunks

  size_t off = 0;
  unsigned short* XB   = wsb + off; off += NX;
  unsigned short* SYB  = wsb + off; off += NX;
  unsigned short* WB[8];
  for (int i = 0; i < 8; ++i) { WB[i] = wsb + off; off += NW; }
  unsigned short* WOSA = wsb + off; off += NO;
  unsigned short* WORA = wsb + off; off += NO;
  unsigned short* Q    = wsb + off; off += NB;
  unsigned short* K    = wsb + off; off += NB;
  unsigned short* V    = wsb + off; off += NB;
  unsigned short* QA   = wsb + off; off += NB;
  unsigned short* KA   = wsb + off; off += NB;
  unsigned short* QR   = wsb + off; off += NB;
  unsigned short* KR   = wsb + off; off += NB;
  unsigned short* SV   = wsb + off; off += NB;
  unsigned short* Asa  = wsb + off; off += NB;
  unsigned short* Ara  = wsb + off; off += NB;
  unsigned short* RelCF = wsb + off; off += NR;
  unsigned short* PoP  = XB;                      // aliases dead XB/SYB/WB[0..3]
  float* lP   = (float*)(wsb + off); off += NCH * 128 * 2;
  float* arpP = (float*)(wsb + off); off += NCH * 1024 * 2;

  CvtJobs cj;
  cj.src[0]  = x;    cj.dst[0]  = XB;    cj.n4[0]  = (int)(NX / 4);
  cj.src[1]  = sym;  cj.dst[1]  = SYB;   cj.n4[1]  = (int)(NX / 4);
  cj.src[2]  = wqsa; cj.dst[2]  = WB[0]; cj.n4[2]  = (int)(NW / 4);
  cj.src[3]  = wksa; cj.dst[3]  = WB[1]; cj.n4[3]  = (int)(NW / 4);
  cj.src[4]  = wvsa; cj.dst[4]  = WB[2]; cj.n4[4]  = (int)(NW / 4);
  cj.src[5]  = wqat; cj.dst[5]  = WB[3]; cj.n4[5]  = (int)(NW / 4);
  cj.src[6]  = wkat; cj.dst[6]  = WB[4]; cj.n4[6]  = (int)(NW / 4);
  cj.src[7]  = wqre; cj.dst[7]  = WB[5]; cj.n4[7]  = (int)(NW / 4);
  cj.src[8]  = wkre; cj.dst[8]  = WB[6]; cj.n4[8]  = (int)(NW / 4);
  cj.src[9]  = wvra; cj.dst[9]  = WB[7]; cj.n4[9]  = (int)(NW / 4);
  cj.src[10] = wosa; cj.dst[10] = WOSA;  cj.n4[10] = (int)(NO / 4);
  cj.src[11] = wora; cj.dst[11] = WORA;  cj.n4[11] = (int)(NO / 4);
  cvt_many<<<dim3(4096, 12), dim3(256), 0, stream>>>(cj);

  proj_tiled<<<dim3(32, 32), dim3(256), 0, stream>>>(XB, SYB, WB[0], Q, SV);
  rel_rope<<<dim3(136, 16), dim3(256), 0, stream>>>(QR, KR, RelCF, Q, K, QA, KA, fc, fs);
  flash_part<<<dim3(NCHK2, 16, B_), dim3(512), 0, stream>>>(
      Q, K, V, QA, KA, SV, RelCF, PoP, lP, arpP);
  flash_merge<<<dim3(NT_, 16, B_), dim3(256), 0, stream>>>(
      PoP, lP, arpP, wr, Asa, Ara);
  out_tiled<<<dim3(32, 16), dim3(256), 0, stream>>>(Asa, Ara, WOSA, WORA, (float*)d_out);
}

// Round 7
// 302.732 us; speedup vs baseline: 1.1677x; 1.1677x over previous
//
#include <hip/hip_runtime.h>

#define B_   2
#define S_   2048
#define H_   8
#define D_   64
#define DM_  1024
#define PJ_  512          // H_*D_ = projection width
#define NT_  32           // S_/64 i-tiles
#define NTRI 528          // NT_*(NT_+1)/2 lower-triangular 64-tiles
#define NCHK2 40          // split-j chunks per (b,hh) over 128-row i-blocks

typedef short bf16x8 __attribute__((ext_vector_type(8)));
typedef float f32x4 __attribute__((ext_vector_type(4)));

__device__ __forceinline__ float bf2f(unsigned int u) {
  return __uint_as_float(u << 16);
}
__device__ __forceinline__ unsigned short f2bf(float f) {
  unsigned int u = __float_as_uint(f);
  u += 0x7fffu + ((u >> 16) & 1u);           // round-to-nearest-even
  return (unsigned short)(u >> 16);
}
// packed f32x2 -> bf16x2 (RNE), gfx950 has no builtin (T12) — inline asm
__device__ __forceinline__ unsigned int cvtpk_bf16(float lo, float hi) {
  unsigned int r;
  asm("v_cvt_pk_bf16_f32 %0, %1, %2" : "=v"(r) : "v"(lo), "v"(hi));
  return r;
}
__device__ __forceinline__ bf16x8 u4_to_bf(uint4 v) {
  union { uint4 a; bf16x8 b; } u; u.a = v; return u.b;
}

// async global->LDS DMA, 16 B/lane; LDS dest = wave-uniform base + lane*16
__device__ __forceinline__ void glds16(const unsigned short* g, unsigned short* l) {
  __builtin_amdgcn_global_load_lds(
      (const __attribute__((address_space(1))) void*)g,
      (__attribute__((address_space(3))) void*)l, 16, 0, 0);
}

// ---------------------------------------------------------------------------
// f32 -> bf16 conversion (12 jobs; wr stays f32 and is read directly).
// ---------------------------------------------------------------------------
struct CvtJobs {
  const float*    src[12];
  unsigned short* dst[12];
  int             n4[12];
};

__global__ __launch_bounds__(256) void cvt_many(CvtJobs J) {
  const int j = blockIdx.y;
  const int i = blockIdx.x * 256 + threadIdx.x;
  if (i >= J.n4[j]) return;
  const float4 v = ((const float4*)J.src[j])[i];
  ushort4 o;
  o.x = f2bf(v.x); o.y = f2bf(v.y); o.z = f2bf(v.z); o.w = f2bf(v.w);
  ((ushort4*)J.dst[j])[i] = o;
}

// ---------------------------------------------------------------------------
// 128x128-tile MFMA GEMM with global_load_lds staging (m97 ladder step).
// ---------------------------------------------------------------------------
__device__ __forceinline__
void gemm128_glds(const unsigned short* __restrict__ A, int m0,
                  const unsigned short* __restrict__ Wb,
                  unsigned short* __restrict__ Cb, int ldc, int KD,
                  unsigned short* As, unsigned short* Bs)
{
  const int tid = threadIdx.x;
  const int wv = tid >> 6, lane = tid & 63;
  const int r15 = lane & 15, quad = lane >> 4;
  const int wm = (wv >> 1) * 64, wn = (wv & 1) * 64;
  f32x4 acc[4][4];
#pragma unroll
  for (int i = 0; i < 4; ++i)
#pragma unroll
    for (int j = 0; j < 4; ++j) acc[i][j] = (f32x4){0.f, 0.f, 0.f, 0.f};

  const int srow = wv * 16 + (lane >> 2);
  const int scol = ((lane & 3) ^ ((lane >> 3) & 3)) * 8;   // xor-swizzled source col
  const unsigned short* gaA0 = A + (size_t)(m0 + srow) * KD + scol;
  const unsigned short* gaA1 = gaA0 + (size_t)64 * KD;
  const unsigned short* gaB0 = Wb + (size_t)srow * KD + scol;
  const unsigned short* gaB1 = gaB0 + (size_t)64 * KD;
  unsigned short* ldsA0 = As + wv * 512;
  unsigned short* ldsA1 = As + 2048 + wv * 512;
  unsigned short* ldsB0 = Bs + wv * 512;
  unsigned short* ldsB1 = Bs + 2048 + wv * 512;
  const int rxor = (r15 >> 1) & 3;                         // read-side xor

  for (int kk = 0; kk < KD; kk += 32) {
    __syncthreads();
    glds16(gaA0 + kk, ldsA0);
    glds16(gaA1 + kk, ldsA1);
    glds16(gaB0 + kk, ldsB0);
    glds16(gaB1 + kk, ldsB1);
    __syncthreads();     // drains vmcnt for the DMA
    bf16x8 af[4], bf[4];
#pragma unroll
    for (int i = 0; i < 4; ++i)
      af[i] = *(const bf16x8*)(As + (wm + i * 16 + r15) * 32 + ((quad ^ rxor) << 3));
#pragma unroll
    for (int j = 0; j < 4; ++j)
      bf[j] = *(const bf16x8*)(Bs + (wn + j * 16 + r15) * 32 + ((quad ^ rxor) << 3));
#pragma unroll
    for (int i = 0; i < 4; ++i)
#pragma unroll
      for (int j = 0; j < 4; ++j)
        acc[i][j] = __builtin_amdgcn_mfma_f32_16x16x32_bf16(af[i], bf[j], acc[i][j], 0, 0, 0);
  }
#pragma unroll
  for (int i = 0; i < 4; ++i)
#pragma unroll
    for (int r = 0; r < 4; ++r) {
      unsigned short* cp = Cb + (size_t)(wm + i * 16 + quad * 4 + r) * ldc + wn + r15;
#pragma unroll
      for (int j = 0; j < 4; ++j) cp[j * 16] = f2bf(acc[i][j][r]);
    }
}

// 8 projection GEMMs in one launch. grid (32, 32)
__global__ __launch_bounds__(256)
void proj_tiled(const unsigned short* __restrict__ XB,
                const unsigned short* __restrict__ SYB,
                const unsigned short* __restrict__ Wcat,
                unsigned short* __restrict__ Qbase,
                unsigned short* __restrict__ SV)
{
  __shared__ unsigned short As[128 * 32];
  __shared__ unsigned short Bs[128 * 32];
  const int m0 = blockIdx.x * 128;
  const int ny = blockIdx.y;
  const size_t NB = (size_t)B_ * S_ * PJ_;
  const unsigned short* A;
  const unsigned short* Wb;
  unsigned short* Cb;
  if (ny < 28) {
    const int n0 = ny * 128;
    A  = XB;
    Wb = Wcat + (size_t)n0 * DM_;
    Cb = Qbase + (size_t)(n0 >> 9) * NB + (size_t)m0 * PJ_ + (n0 & 511);
  } else {
    const int n0 = (ny - 28) * 128;
    A  = SYB;
    Wb = Wcat + (size_t)7 * PJ_ * DM_ + (size_t)n0 * DM_;
    Cb = SV + (size_t)m0 * PJ_ + n0;
  }
  gemm128_glds(A, m0, Wb, Cb, PJ_, DM_, As, Bs);
}

// ---------------------------------------------------------------------------
// Output projections: 128m x 64n tiles (512 blocks). grid (32, 16).
// ---------------------------------------------------------------------------
__global__ __launch_bounds__(256)
void out_tiled(const unsigned short* __restrict__ Asa,
               const unsigned short* __restrict__ Ara,
               const unsigned short* __restrict__ WOSA,
               const unsigned short* __restrict__ WORA,
               float* __restrict__ Out)
{
  __shared__ unsigned short As[128 * 40];
  __shared__ unsigned short Bs[64 * 40];
  const int m0 = blockIdx.x * 128;
  const int ny = blockIdx.y;
  const int n0 = (ny & 7) * 64;
  const unsigned short* A  = (ny < 8) ? Asa : Ara;
  const unsigned short* Wb = ((ny < 8) ? WOSA : WORA) + (size_t)n0 * PJ_;
  float* Cb = Out + (size_t)m0 * DM_ + ((ny < 8) ? 0 : 512) + n0;

  const int tid = threadIdx.x;
  const int wv = tid >> 6, lane = tid & 63;
  const int r15 = lane & 15, quad = lane >> 4;
  const int wm = wv * 32;
  f32x4 acc[2][4];
#pragma unroll
  for (int i = 0; i < 2; ++i)
#pragma unroll
    for (int j = 0; j < 4; ++j) acc[i][j] = (f32x4){0.f, 0.f, 0.f, 0.f};

  const int arow = tid >> 1, ac = (tid & 1) * 16;
  const int brow = tid >> 2, bc = (tid & 3) * 8;
  const unsigned short* ga = A + (size_t)(m0 + arow) * PJ_ + ac;
  const unsigned short* gb = Wb + (size_t)brow * PJ_ + bc;
  unsigned short* la = As + arow * 40 + ac;
  unsigned short* lb = Bs + brow * 40 + bc;

  for (int kk = 0; kk < PJ_; kk += 32) {
    __syncthreads();
    const uint4 a0 = *(const uint4*)(ga + kk);
    const uint4 a1 = *(const uint4*)(ga + kk + 8);
    const uint4 b0 = *(const uint4*)(gb + kk);
    *(uint4*)la       = a0;
    *(uint4*)(la + 8) = a1;
    *(uint4*)lb       = b0;
    __syncthreads();
    bf16x8 af[2], bf[4];
#pragma unroll
    for (int i = 0; i < 2; ++i)
      af[i] = *(const bf16x8*)(As + (wm + i * 16 + r15) * 40 + quad * 8);
#pragma unroll
    for (int j = 0; j < 4; ++j)
      bf[j] = *(const bf16x8*)(Bs + (j * 16 + r15) * 40 + quad * 8);
#pragma unroll
    for (int i = 0; i < 2; ++i)
#pragma unroll
      for (int j = 0; j < 4; ++j)
        acc[i][j] = __builtin_amdgcn_mfma_f32_16x16x32_bf16(af[i], bf[j], acc[i][j], 0, 0, 0);
  }
#pragma unroll
  for (int i = 0; i < 2; ++i)
#pragma unroll
    for (int r = 0; r < 4; ++r) {
      float* cp = Cb + (size_t)(wm + i * 16 + quad * 4 + r) * DM_ + r15;
#pragma unroll
      for (int j = 0; j < 4; ++j) cp[j * 16] = acc[i][j][r];
    }
}

// ---------------------------------------------------------------------------
// rel materialization (tri-128 LDS GEMM), FUSED with vectorized RoPE.
// Tiles stored in B-frag-sigma order so flash_part feeds them DIRECTLY into
// MFMA as the second operand (arp-as-MFMA):
//   flat tile index = sub*1024 + k0*512 + lane*8 + jj  holds
//   rel[i' = sub*16 + (lane&15)][j = ((k0<<1)|(jj>>2))*16 + (lane>>4)*4 + (jj&3)]
// grid (136, 16).
// ---------------------------------------------------------------------------
__global__ __launch_bounds__(256)
void rel_rope(const unsigned short* __restrict__ QRg, const unsigned short* __restrict__ KRg,
              unsigned short* __restrict__ RelCF,
              unsigned short* __restrict__ Qp, unsigned short* __restrict__ Kp,
              unsigned short* __restrict__ QAp, unsigned short* __restrict__ KAp,
              const float* __restrict__ fcp, const float* __restrict__ fsp)
{
  __shared__ unsigned short As[128 * 72];
  __shared__ unsigned short Bs[128 * 72];
  const int t = blockIdx.x;
  int I = 0;
  while ((I + 1) * (I + 2) / 2 <= t) ++I;
  const int J = t - I * (I + 1) / 2;
  const int rr = blockIdx.y & 7, b = blockIdx.y >> 3;
  const int tid = threadIdx.x;
  const int wv = tid >> 6, lane = tid & 63;
  const int r15 = lane & 15, quad = lane >> 4;

  const int srow = tid >> 1, c32 = (tid & 1) * 32;
  const unsigned short* ga = QRg + (size_t)(b * S_ + I * 128 + srow) * PJ_ + rr * 64 + c32;
  const unsigned short* gb = KRg + (size_t)(b * S_ + J * 128 + srow) * PJ_ + rr * 64 + c32;
  unsigned short* la = As + srow * 72 + c32;
  unsigned short* lb = Bs + srow * 72 + c32;
#pragma unroll
  for (int q = 0; q < 4; ++q) {
    *(uint4*)(la + q * 8) = *(const uint4*)(ga + q * 8);
    *(uint4*)(lb + q * 8) = *(const uint4*)(gb + q * 8);
  }
  __syncthreads();

  const int wm = (wv >> 1) * 64, wn = (wv & 1) * 64;
  const int it64 = 2 * I + (wv >> 1), jt64 = 2 * J + (wv & 1);
  if (jt64 <= it64) {
    f32x4 acc[4][4];           // acc[a][b]: a = j-16-block, b = i-16-block
#pragma unroll
    for (int a = 0; a < 4; ++a)
#pragma unroll
      for (int bq = 0; bq < 4; ++bq) acc[a][bq] = (f32x4){0.f, 0.f, 0.f, 0.f};
#pragma unroll
    for (int k0 = 0; k0 < 2; ++k0) {
      bf16x8 af[4], bf[4];
#pragma unroll
      for (int i = 0; i < 4; ++i)
        af[i] = *(const bf16x8*)(As + (wm + i * 16 + r15) * 72 + quad * 8 + k0 * 32);
#pragma unroll
      for (int j = 0; j < 4; ++j)
        bf[j] = *(const bf16x8*)(Bs + (wn + j * 16 + r15) * 72 + quad * 8 + k0 * 32);
#pragma unroll
      for (int a = 0; a < 4; ++a)
#pragma unroll
        for (int bq = 0; bq < 4; ++bq)
          acc[a][bq] = __builtin_amdgcn_mfma_f32_16x16x32_bf16(bf[a], af[bq], acc[a][bq], 0, 0, 0);
    }
    unsigned short* out = RelCF + ((size_t)(b * 8 + rr) * NTRI + (size_t)it64 * (it64 + 1) / 2 + jt64) * 4096;
#pragma unroll
    for (int bq = 0; bq < 4; ++bq) {
      unsigned short tmp[16];
#pragma unroll
      for (int a = 0; a < 4; ++a)
#pragma unroll
        for (int r = 0; r < 4; ++r)
          tmp[a * 4 + r] = f2bf(acc[a][bq][r] * 0.125f);
      unsigned short* op = out + (size_t)bq * 1024 + (size_t)lane * 8;   // k0=0 half
      *(uint4*)op         = *(const uint4*)tmp;
      *(uint4*)(op + 512) = *(const uint4*)(tmp + 8);                    // k0=1 half
    }
  }

  // ---- fused RoPE (all threads): 2 uint4 slices of {Q,K,QA,KA} each ----
  // per-tensor uint4 count = NB/8 = 262144 = 2^18; total = 4*2^18 = 1048576.
  const int bid = (int)blockIdx.y * 136 + (int)blockIdx.x;
  const int gt = bid * 256 + tid;
#pragma unroll
  for (int k = 0; k < 2; ++k) {
    const int i = gt * 2 + k;
    if (i >= 4 * 262144) continue;
    const int tn = i >> 18;
    const int r2 = i & 262143;
    unsigned short* P = (tn == 0) ? Qp : (tn == 1) ? Kp : (tn == 2) ? QAp : KAp;
    const int b2 = r2 >> 17;                  // 131072 uint4 per batch
    const int s2 = (r2 >> 6) & 2047;          // 64 uint4 per 512-wide row
    const int c8 = (r2 & 63) * 8;             // column offset (elements)
    const int ci0 = (c8 & 63) >> 1;           // first rotary index of 4 pairs
    const size_t off2 = ((size_t)(b2 * S_ + s2)) * PJ_ + c8;
    uint4 v = *(const uint4*)(P + off2);
    unsigned int u[4] = {v.x, v.y, v.z, v.w};
    unsigned int o[4];
#pragma unroll
    for (int q = 0; q < 4; ++q) {
      const float xr = __uint_as_float(u[q] << 16);
      const float xi = __uint_as_float(u[q] & 0xffff0000u);
      const float cs = fcp[s2 * 32 + ci0 + q];
      const float sn = fsp[s2 * 32 + ci0 + q];
      const unsigned short lo = f2bf(xr * cs - xi * sn);
      const unsigned short hi = f2bf(xr * sn + xi * cs);
      o[q] = (unsigned int)lo | ((unsigned int)hi << 16);
    }
    uint4 ov; ov.x = o[0]; ov.y = o[1]; ov.z = o[2]; ov.w = o[3];
    *(uint4*)(P + off2) = ov;
  }
}

// ---------------------------------------------------------------------------
// Split-j flash partial pass — r21: REVERT to the r19 structure (proven
// 92 µs: K+V staged in LDS, 128-row i-blocks, 8 waves, KVBLK=128, double-
// buffered, no launch-bounds clamp, no setprio).  r20's K-direct-from-global
// regressed 92->143: it put 8 dependent, scatter-pattern global loads on the
// QK critical path of every tile with nothing covering them (all util
// counters fell).  Kept from r20's idea, the two safe deltas:
//  * masked-tile skip: wave-uniform jtt > it_wave early-out (TILE has no
//    barriers, so per-wave return is sync-safe).
//  * software-pipelined rel rr=4..7: issue rr+1's two uint4 loads before
//    rr's MFMAs so L3 latency overlaps the MFMA stream (r19 exposed
//    ~300-500 cyc per iteration).  +8 transient VGPR.
// grid (40, 16, 2). Partials per chunk: Po bf16 128x64, l f32 128, arp f32 128x8.
// ---------------------------------------------------------------------------
__global__ __launch_bounds__(512)
void flash_part(const unsigned short* __restrict__ Qsa, const unsigned short* __restrict__ Ksa,
                const unsigned short* __restrict__ Vsa,
                const unsigned short* __restrict__ Qra, const unsigned short* __restrict__ Kra,
                const unsigned short* __restrict__ SVra,
                const unsigned short* __restrict__ RelCF,
                unsigned short* __restrict__ PoP, float* __restrict__ lP,
                float* __restrict__ arpP)
{
  __shared__ unsigned short Ks[2][2][64][72];
  __shared__ unsigned short Vt[2][2][64][72];   // [buf][tile][d][kslot]
  const int x = NCHK2 - 1 - (int)blockIdx.x;    // big chunks dispatch first
  int a, c;
  if (x < 4)       { a = x;                 c = 0; }
  else if (x < 12) { a = 4 + ((x - 4) >> 1);  c = (x - 4) & 1; }
  else if (x < 24) { a = 8 + (x - 12) / 3;    c = (x - 12) % 3; }
  else             { a = 12 + ((x - 24) >> 2); c = (x - 24) & 3; }
  const int j0 = c * 8;
  const int jendF = 2 * a + 2;
  const int jend = (j0 + 8 < jendF) ? (j0 + 8) : jendF;   // always even
  const bool ra = (blockIdx.y >= 8);
  const int h = blockIdx.y & 7;
  const int b = blockIdx.z;
  const int chunkId = (b * 16 + (int)blockIdx.y) * NCHK2 + x;
  const unsigned short* Qg = ra ? Qra : Qsa;
  const unsigned short* Kg = ra ? Kra : Ksa;
  const unsigned short* Vg = ra ? SVra : Vsa;
  const int tid = threadIdx.x;
  const int wv = tid >> 6, lane = tid & 63;
  const int r15 = lane & 15, quad = lane >> 4;
  const size_t bh = (size_t)b * S_ * PJ_ + (size_t)h * D_;
  const size_t relStride = (size_t)NTRI * 4096;
  const int it_wave = 2 * a + (wv >> 2);        // wave-uniform
  const int gi = a * 128 + wv * 16 + r15;       // lane's global i-row

  // staging addresses (per-thread constants); 512 threads: one uint4 per tile
  const int kr = tid >> 3, kc0 = (tid & 7) << 3;          // K: row 0..63, col
  const unsigned short* kgp = Kg + bh + (size_t)kr * PJ_ + kc0;
  const unsigned short* vgp = Vg + bh + (size_t)lane * PJ_ + wv * 8;  // V row=lane, d=wv*8..+7
  // sigma^-1: k-slot for this thread's staged V column (j = lane)
  const int kcol = ((lane >> 2) & 3) * 8 + ((lane >> 4) & 1) * 4 + (lane & 3) + (lane >> 5) * 32;

  // Q fragments in registers (layout: row=r15, k=quad*8+j — serves as B-frag)
  const unsigned short* qp = Qg + bh + (size_t)gi * PJ_ + quad * 8;
  const bf16x8 aq0 = *(const bf16x8*)qp;
  const bf16x8 aq1 = *(const bf16x8*)(qp + 32);

  const bf16x8 ones = (bf16x8)(short)0x3F80;   // bf16 1.0 splat (B-frag for l)

  f32x4 o_acc[4];
  f32x4 l_acc = (f32x4){0.f, 0.f, 0.f, 0.f};
  f32x4 accR[8];                               // arp MFMA accumulators (ra only)
#pragma unroll
  for (int n = 0; n < 4; ++n) o_acc[n] = (f32x4){0.f, 0.f, 0.f, 0.f};
#pragma unroll
  for (int rr = 0; rr < 8; ++rr) accR[rr] = (f32x4){0.f, 0.f, 0.f, 0.f};
  // B-frag-sigma rel tile base for this wave's 64-tile row (it_wave)
  const size_t relTileBase = (size_t)(b * 8) * NTRI * 4096
                           + (size_t)(it_wave * (it_wave + 1)) / 2 * 4096
                           + (size_t)(wv & 3) * 1024 + (size_t)lane * 8;

  // one j-tile's QK/softmax/l/arp/PV from buffer slot (KsT, VtT)
  auto TILE = [&](int jtt, const unsigned short (*KsT)[72], const unsigned short (*VtT)[72]) {
    if (jtt > it_wave) return;                 // fully-masked tile: exact 0 contribution
    const unsigned short* rtBase = RelCF + relTileBase + (size_t)jtt * 4096;
    uint4 pre[8];
    if (ra) {
      const unsigned short* rt = rtBase;
#pragma unroll
      for (int q = 0; q < 4; ++q) {
        pre[2 * q]     = *(const uint4*)rt;
        pre[2 * q + 1] = *(const uint4*)(rt + 512);
        rt += relStride;
      }
    }
    // QK^T, SWAPPED operands: lane row i=gi, j = jtt*64 + n*16 + quad*4 + r
    f32x4 s[4];
#pragma unroll
    for (int n = 0; n < 4; ++n) s[n] = (f32x4){0.f, 0.f, 0.f, 0.f};
#pragma unroll
    for (int k0 = 0; k0 < 2; ++k0) {
      const bf16x8 bq = k0 ? aq1 : aq0;
#pragma unroll
      for (int n = 0; n < 4; ++n) {
        const bf16x8 kf = *(const bf16x8*)&KsT[n * 16 + r15][quad * 8 + k0 * 32];
        s[n] = __builtin_amdgcn_mfma_f32_16x16x32_bf16(kf, bq, s[n], 0, 0, 0);
      }
    }
    // fixed-shift softmax: exp(s*0.125-4) = exp2(fma(s, log2e/8, -4log2e))
    if (jtt == it_wave) {   // diagonal tile
#pragma unroll
      for (int n = 0; n < 4; ++n)
#pragma unroll
        for (int r = 0; r < 4; ++r) {
          const bool ok = (jtt * 64 + n * 16 + quad * 4 + r <= gi);
          s[n][r] = ok ? exp2f(fmaf(s[n][r], 0.180336887f, -5.770780163f)) : 0.f;
        }
    } else {
#pragma unroll
      for (int n = 0; n < 4; ++n)
#pragma unroll
        for (int r = 0; r < 4; ++r)
          s[n][r] = exp2f(fmaf(s[n][r], 0.180336887f, -5.770780163f));
    }
    // packed P->bf16 under sigma
    uint4 w0, w1;
    w0.x = cvtpk_bf16(s[0][0], s[0][1]); w0.y = cvtpk_bf16(s[0][2], s[0][3]);
    w0.z = cvtpk_bf16(s[1][0], s[1][1]); w0.w = cvtpk_bf16(s[1][2], s[1][3]);
    w1.x = cvtpk_bf16(s[2][0], s[2][1]); w1.y = cvtpk_bf16(s[2][2], s[2][3]);
    w1.z = cvtpk_bf16(s[3][0], s[3][1]); w1.w = cvtpk_bf16(s[3][2], s[3][3]);
    const bf16x8 pa0 = u4_to_bf(w0);
    const bf16x8 pa1 = u4_to_bf(w1);
    // l via MFMA against constant ones B-frag
    l_acc = __builtin_amdgcn_mfma_f32_16x16x32_bf16(pa0, ones, l_acc, 0, 0, 0);
    l_acc = __builtin_amdgcn_mfma_f32_16x16x32_bf16(pa1, ones, l_acc, 0, 0, 0);
    // arp MFMAs rr=0..3 (diag of D = arp; frags fully prefetched in pre[])
    if (ra) {
#pragma unroll
      for (int rr = 0; rr < 4; ++rr) {
        accR[rr] = __builtin_amdgcn_mfma_f32_16x16x32_bf16(pa0, u4_to_bf(pre[2 * rr]), accR[rr], 0, 0, 0);
        accR[rr] = __builtin_amdgcn_mfma_f32_16x16x32_bf16(pa1, u4_to_bf(pre[2 * rr + 1]), accR[rr], 0, 0, 0);
      }
    }
    // PV: 8 MFMAs (Vt columns are sigma-permuted)
#pragma unroll
    for (int k0 = 0; k0 < 2; ++k0) {
      const bf16x8 pf = k0 ? pa1 : pa0;
#pragma unroll
      for (int n = 0; n < 4; ++n) {
        const bf16x8 vf = *(const bf16x8*)&VtT[n * 16 + r15][quad * 8 + k0 * 32];
        o_acc[n] = __builtin_amdgcn_mfma_f32_16x16x32_bf16(pf, vf, o_acc[n], 0, 0, 0);
      }
    }
    // arp MFMAs rr=4..7 — 1-deep software pipeline: issue rr+1's loads
    // before rr's MFMAs so the L3 latency hides under the MFMA stream
    if (ra) {
      const unsigned short* rt2 = rtBase + 4 * relStride;
      uint4 nb0 = *(const uint4*)rt2;
      uint4 nb1 = *(const uint4*)(rt2 + 512);
#pragma unroll
      for (int rr = 4; rr < 8; ++rr) {
        const bf16x8 rb0 = u4_to_bf(nb0);
        const bf16x8 rb1 = u4_to_bf(nb1);
        if (rr < 7) {
          rt2 += relStride;
          nb0 = *(const uint4*)rt2;
          nb1 = *(const uint4*)(rt2 + 512);
        }
        accR[rr] = __builtin_amdgcn_mfma_f32_16x16x32_bf16(pa0, rb0, accR[rr], 0, 0, 0);
        accR[rr] = __builtin_amdgcn_mfma_f32_16x16x32_bf16(pa1, rb1, accR[rr], 0, 0, 0);
      }
    }
  };

  // prologue: load round (j0, j0+1), store to buf 0
  uint4 ka0, ka1, va0, va1;
  {
    const size_t jb0 = (size_t)j0 * 64 * PJ_;
    const size_t jb1 = (size_t)(j0 + 1) * 64 * PJ_;
    ka0 = *(const uint4*)(kgp + jb0);
    ka1 = *(const uint4*)(kgp + jb1);
    va0 = *(const uint4*)(vgp + jb0);
    va1 = *(const uint4*)(vgp + jb1);
  }
  int p = 0;
  {
    *(uint4*)&Ks[0][0][kr][kc0] = ka0;
    *(uint4*)&Ks[0][1][kr][kc0] = ka1;
    unsigned short t8[8];
    *(uint4*)t8 = va0;
#pragma unroll
    for (int m = 0; m < 8; ++m) Vt[0][0][wv * 8 + m][kcol] = t8[m];
    *(uint4*)t8 = va1;
#pragma unroll
    for (int m = 0; m < 8; ++m) Vt[0][1][wv * 8 + m][kcol] = t8[m];
  }
  __syncthreads();

  for (int jt = j0; jt < jend; jt += 2) {
    const bool more = (jt + 2 < jend);
    if (more) {   // issue next round's loads (2 tiles of compute to hide)
      const size_t jb0 = (size_t)(jt + 2) * 64 * PJ_;
      const size_t jb1 = (size_t)(jt + 3) * 64 * PJ_;
      ka0 = *(const uint4*)(kgp + jb0);
      ka1 = *(const uint4*)(kgp + jb1);
      va0 = *(const uint4*)(vgp + jb0);
      va1 = *(const uint4*)(vgp + jb1);
    }
    TILE(jt,     Ks[p][0], Vt[p][0]);
    TILE(jt + 1, Ks[p][1], Vt[p][1]);
    if (more) {
      const int q = p ^ 1;
      *(uint4*)&Ks[q][0][kr][kc0] = ka0;
      *(uint4*)&Ks[q][1][kr][kc0] = ka1;
      unsigned short t8[8];
      *(uint4*)t8 = va0;
#pragma unroll
      for (int m = 0; m < 8; ++m) Vt[q][0][wv * 8 + m][kcol] = t8[m];
      *(uint4*)t8 = va1;
#pragma unroll
      for (int m = 0; m < 8; ++m) Vt[q][1][wv * 8 + m][kcol] = t8[m];
      __syncthreads();
      p = q;
    }
  }
  // ---- write partials (chunk: Po 128x64, l 128, arp 128x8) ----
  unsigned short* po = PoP + (size_t)chunkId * 8192;
#pragma unroll
  for (int n = 0; n < 4; ++n)
#pragma unroll
    for (int r = 0; r < 4; ++r)
      po[(wv * 16 + quad * 4 + r) * 64 + n * 16 + r15] = f2bf(o_acc[n][r]);
  if (r15 == 0) {
#pragma unroll
    for (int r = 0; r < 4; ++r)
      lP[(size_t)chunkId * 128 + wv * 16 + quad * 4 + r] = l_acc[r];
  }
  // arp: diagonal lanes (quad == r15>>2) hold the full j-sum in comp r15&3
  if (ra && quad == (r15 >> 2)) {
    const int d3 = r15 & 3;
    float* ap = arpP + (size_t)chunkId * 1024 + (size_t)(wv * 16 + r15) * 8;
#pragma unroll
    for (int rr = 0; rr < 8; ++rr) {
      const f32x4 a4 = accR[rr];
      const float v = (d3 == 0) ? a4[0] : (d3 == 1) ? a4[1] : (d3 == 2) ? a4[2] : a4[3];
      ap[rr] = v;
    }
  }
}

// ---------------------------------------------------------------------------
// Merge split-j partials (pure sums) + wr (f32) epilogue. grid (32, 16, 2).
// Chunks are 128-row i-blocks; tile it -> block a = it>>1, half = it&1.
// ---------------------------------------------------------------------------
__global__ __launch_bounds__(256)
void flash_merge(const unsigned short* __restrict__ PoP, const float* __restrict__ lP,
                 const float* __restrict__ arpP, const float* __restrict__ wrF,
                 unsigned short* __restrict__ Osa, unsigned short* __restrict__ Ora)
{
  const int it = blockIdx.x;
  const int hh = blockIdx.y;
  const int b  = blockIdx.z;
  const bool ra = (hh >= 8);
  const int h = hh & 7;
  const int a  = it >> 1;
  const int half = it & 1;
  const int nc = ((2 * a + 1) >> 3) + 1;
  int cb;
  if (a < 4)       cb = a;
  else if (a < 8)  cb = 4 + 2 * (a - 4);
  else if (a < 12) cb = 12 + 3 * (a - 8);
  else             cb = 24 + 4 * (a - 12);
  const int cid0 = (b * 16 + hh) * NCHK2 + cb;
  const int tid = threadIdx.x;
  const int row = tid >> 2;            // 0..63 within this 64-row half
  const int cg  = tid & 3;
  const int prow = half * 64 + row;    // row within the 128-row chunk

  float L = 0.f;
  for (int c = 0; c < nc; ++c) L += lP[(size_t)(cid0 + c) * 128 + prow];
  const float inv = 1.f / L;

  float o[16];
#pragma unroll
  for (int k = 0; k < 16; ++k) o[k] = 0.f;
  for (int c = 0; c < nc; ++c) {
    const unsigned short* pp = PoP + (size_t)(cid0 + c) * 8192 + prow * 64 + cg * 16;
    unsigned int u[8];
    *(uint4*)u       = *(const uint4*)pp;
    *(uint4*)(u + 4) = *(const uint4*)(pp + 8);
#pragma unroll
    for (int q = 0; q < 8; ++q) {
      o[2 * q]     += __uint_as_float(u[q] << 16);
      o[2 * q + 1] += __uint_as_float(u[q] & 0xffff0000u);
    }
  }
  if (ra) {
    float A[8];
#pragma unroll
    for (int rr = 0; rr < 8; ++rr) A[rr] = 0.f;
    for (int c = 0; c < nc; ++c) {
      const float* ap = arpP + (size_t)(cid0 + c) * 1024 + (size_t)prow * 8;
#pragma unroll
      for (int rr = 0; rr < 8; ++rr) A[rr] += ap[rr];
    }
#pragma unroll
    for (int k = 0; k < 16; ++k) {
      const float* wp = wrF + ((size_t)h * 64 + cg * 16 + k) * 8;
      float ro = 0.f;
#pragma unroll
      for (int rr = 0; rr < 8; ++rr) ro += A[rr] * wp[rr];
      o[k] += ro;
    }
  }
  const size_t bh = (size_t)b * S_ * PJ_ + (size_t)h * D_;
  unsigned short* op = (ra ? Ora : Osa) + bh + (size_t)(it * 64 + row) * PJ_ + cg * 16;
#pragma unroll
  for (int k = 0; k < 16; ++k) op[k] = f2bf(o[k] * inv);
}

// ---------------------------------------------------------------------------
extern "C" void kernel_launch(void* const* d_in, const int* in_sizes, int n_in,
                              void* d_out, int out_size, void* d_ws, size_t ws_size,
                              hipStream_t stream)
{
  (void)in_sizes; (void)n_in; (void)out_size; (void)ws_size;
  const float* x    = (const float*)d_in[0];
  const float* sym  = (const float*)d_in[1];
  const float* fc   = (const float*)d_in[2];
  const float* fs   = (const float*)d_in[3];
  const float* wqsa = (const float*)d_in[4];
  const float* wksa = (const float*)d_in[5];
  const float* wvsa = (const float*)d_in[6];
  const float* wosa = (const float*)d_in[7];
  const float* wqat = (const float*)d_in[8];
  const float* wkat = (const float*)d_in[9];
  const float* wqre = (const float*)d_in[10];
  const float* wkre = (const float*)d_in[11];
  const float* wr   = (const float*)d_in[12];
  const float* wvra = (const float*)d_in[13];
  const float* wora = (const float*)d_in[14];

  unsigned short* wsb = (unsigned short*)d_ws;
  const size_t NX = (size_t)B_ * S_ * DM_;
  const size_t NB = (size_t)B_ * S_ * PJ_;
  const size_t NW = (size_t)PJ_ * DM_;
  const size_t NO = (size_t)PJ_ * PJ_;
  const size_t NR = (size_t)B_ * 8 * NTRI * 4096;
  const size_t NCH = (size_t)B_ * 16 * NCHK2;   // 1280 chunks

  size_t off = 0;
  unsigned short* XB   = wsb + off; off += NX;
  unsigned short* SYB  = wsb + off; off += NX;
  unsigned short* WB[8];
  for (int i = 0; i < 8; ++i) { WB[i] = wsb + off; off += NW; }
  unsigned short* WOSA = wsb + off; off += NO;
  unsigned short* WORA = wsb + off; off += NO;
  unsigned short* Q    = wsb + off; off += NB;
  unsigned short* K    = wsb + off; off += NB;
  unsigned short* V    = wsb + off; off += NB;
  unsigned short* QA   = wsb + off; off += NB;
  unsigned short* KA   = wsb + off; off += NB;
  unsigned short* QR   = wsb + off; off += NB;
  unsigned short* KR   = wsb + off; off += NB;
  unsigned short* SV   = wsb + off; off += NB;
  unsigned short* Asa  = wsb + off; off += NB;
  unsigned short* Ara  = wsb + off; off += NB;
  unsigned short* RelCF = wsb + off; off += NR;
  unsigned short* PoP  = XB;                      // aliases dead XB/SYB/WB[0..3]
  float* lP   = (float*)(wsb + off); off += NCH * 128 * 2;
  float* arpP = (float*)(wsb + off); off += NCH * 1024 * 2;

  CvtJobs cj;
  cj.src[0]  = x;    cj.dst[0]  = XB;    cj.n4[0]  = (int)(NX / 4);
  cj.src[1]  = sym;  cj.dst[1]  = SYB;   cj.n4[1]  = (int)(NX / 4);
  cj.src[2]  = wqsa; cj.dst[2]  = WB[0]; cj.n4[2]  = (int)(NW / 4);
  cj.src[3]  = wksa; cj.dst[3]  = WB[1]; cj.n4[3]  = (int)(NW / 4);
  cj.src[4]  = wvsa; cj.dst[4]  = WB[2]; cj.n4[4]  = (int)(NW / 4);
  cj.src[5]  = wqat; cj.dst[5]  = WB[3]; cj.n4[5]  = (int)(NW / 4);
  cj.src[6]  = wkat; cj.dst[6]  = WB[4]; cj.n4[6]  = (int)(NW / 4);
  cj.src[7]  = wqre; cj.dst[7]  = WB[5]; cj.n4[7]  = (int)(NW / 4);
  cj.src[8]  = wkre; cj.dst[8]  = WB[6]; cj.n4[8]  = (int)(NW / 4);
  cj.src[9]  = wvra; cj.dst[9]  = WB[7]; cj.n4[9]  = (int)(NW / 4);
  cj.src[10] = wosa; cj.dst[10] = WOSA;  cj.n4[10] = (int)(NO / 4);
  cj.src[11] = wora; cj.dst[11] = WORA;  cj.n4[11] = (int)(NO / 4);
  cvt_many<<<dim3(4096, 12), dim3(256), 0, stream>>>(cj);

  proj_tiled<<<dim3(32, 32), dim3(256), 0, stream>>>(XB, SYB, WB[0], Q, SV);
  rel_rope<<<dim3(136, 16), dim3(256), 0, stream>>>(QR, KR, RelCF, Q, K, QA, KA, fc, fs);
  flash_part<<<dim3(NCHK2, 16, B_), dim3(512), 0, stream>>>(
      Q, K, V, QA, KA, SV, RelCF, PoP, lP, arpP);
  flash_merge<<<dim3(NT_, 16, B_), dim3(256), 0, stream>>>(
      PoP, lP, arpP, wr, Asa, Ara);
  out_tiled<<<dim3(32, 16), dim3(256), 0, stream>>>(Asa, Ara, WOSA, WORA, (float*)d_out);
}

// Round 8
// 301.466 us; speedup vs baseline: 1.1726x; 1.0042x over previous
//
#include <hip/hip_runtime.h>

#define B_   2
#define S_   2048
#define H_   8
#define D_   64
#define DM_  1024
#define PJ_  512          // H_*D_ = projection width
#define NT_  32           // S_/64 i-tiles
#define NTRI 528          // NT_*(NT_+1)/2 lower-triangular 64-tiles
#define NCHK2 40          // split-j chunks per (b,hh) over 128-row i-blocks

typedef short bf16x8 __attribute__((ext_vector_type(8)));
typedef float f32x4 __attribute__((ext_vector_type(4)));

__device__ __forceinline__ float bf2f(unsigned int u) {
  return __uint_as_float(u << 16);
}
__device__ __forceinline__ unsigned short f2bf(float f) {
  unsigned int u = __float_as_uint(f);
  u += 0x7fffu + ((u >> 16) & 1u);           // round-to-nearest-even
  return (unsigned short)(u >> 16);
}
// packed f32x2 -> bf16x2 (RNE), gfx950 has no builtin (T12) — inline asm
__device__ __forceinline__ unsigned int cvtpk_bf16(float lo, float hi) {
  unsigned int r;
  asm("v_cvt_pk_bf16_f32 %0, %1, %2" : "=v"(r) : "v"(lo), "v"(hi));
  return r;
}
__device__ __forceinline__ bf16x8 u4_to_bf(uint4 v) {
  union { uint4 a; bf16x8 b; } u; u.a = v; return u.b;
}

// async global->LDS DMA, 16 B/lane; LDS dest = wave-uniform base + lane*16
__device__ __forceinline__ void glds16(const unsigned short* g, unsigned short* l) {
  __builtin_amdgcn_global_load_lds(
      (const __attribute__((address_space(1))) void*)g,
      (__attribute__((address_space(3))) void*)l, 16, 0, 0);
}

// ---------------------------------------------------------------------------
// f32 -> bf16 conversion (12 jobs; wr stays f32 and is read directly).
// ---------------------------------------------------------------------------
struct CvtJobs {
  const float*    src[12];
  unsigned short* dst[12];
  int             n4[12];
};

__global__ __launch_bounds__(256) void cvt_many(CvtJobs J) {
  const int j = blockIdx.y;
  const int i = blockIdx.x * 256 + threadIdx.x;
  if (i >= J.n4[j]) return;
  const float4 v = ((const float4*)J.src[j])[i];
  ushort4 o;
  o.x = f2bf(v.x); o.y = f2bf(v.y); o.z = f2bf(v.z); o.w = f2bf(v.w);
  ((ushort4*)J.dst[j])[i] = o;
}

// ---------------------------------------------------------------------------
// 128x128-tile MFMA GEMM with global_load_lds staging (m97 ladder step).
// ---------------------------------------------------------------------------
__device__ __forceinline__
void gemm128_glds(const unsigned short* __restrict__ A, int m0,
                  const unsigned short* __restrict__ Wb,
                  unsigned short* __restrict__ Cb, int ldc, int KD,
                  unsigned short* As, unsigned short* Bs)
{
  const int tid = threadIdx.x;
  const int wv = tid >> 6, lane = tid & 63;
  const int r15 = lane & 15, quad = lane >> 4;
  const int wm = (wv >> 1) * 64, wn = (wv & 1) * 64;
  f32x4 acc[4][4];
#pragma unroll
  for (int i = 0; i < 4; ++i)
#pragma unroll
    for (int j = 0; j < 4; ++j) acc[i][j] = (f32x4){0.f, 0.f, 0.f, 0.f};

  const int srow = wv * 16 + (lane >> 2);
  const int scol = ((lane & 3) ^ ((lane >> 3) & 3)) * 8;   // xor-swizzled source col
  const unsigned short* gaA0 = A + (size_t)(m0 + srow) * KD + scol;
  const unsigned short* gaA1 = gaA0 + (size_t)64 * KD;
  const unsigned short* gaB0 = Wb + (size_t)srow * KD + scol;
  const unsigned short* gaB1 = gaB0 + (size_t)64 * KD;
  unsigned short* ldsA0 = As + wv * 512;
  unsigned short* ldsA1 = As + 2048 + wv * 512;
  unsigned short* ldsB0 = Bs + wv * 512;
  unsigned short* ldsB1 = Bs + 2048 + wv * 512;
  const int rxor = (r15 >> 1) & 3;                         // read-side xor

  for (int kk = 0; kk < KD; kk += 32) {
    __syncthreads();
    glds16(gaA0 + kk, ldsA0);
    glds16(gaA1 + kk, ldsA1);
    glds16(gaB0 + kk, ldsB0);
    glds16(gaB1 + kk, ldsB1);
    __syncthreads();     // drains vmcnt for the DMA
    bf16x8 af[4], bf[4];
#pragma unroll
    for (int i = 0; i < 4; ++i)
      af[i] = *(const bf16x8*)(As + (wm + i * 16 + r15) * 32 + ((quad ^ rxor) << 3));
#pragma unroll
    for (int j = 0; j < 4; ++j)
      bf[j] = *(const bf16x8*)(Bs + (wn + j * 16 + r15) * 32 + ((quad ^ rxor) << 3));
#pragma unroll
    for (int i = 0; i < 4; ++i)
#pragma unroll
      for (int j = 0; j < 4; ++j)
        acc[i][j] = __builtin_amdgcn_mfma_f32_16x16x32_bf16(af[i], bf[j], acc[i][j], 0, 0, 0);
  }
#pragma unroll
  for (int i = 0; i < 4; ++i)
#pragma unroll
    for (int r = 0; r < 4; ++r) {
      unsigned short* cp = Cb + (size_t)(wm + i * 16 + quad * 4 + r) * ldc + wn + r15;
#pragma unroll
      for (int j = 0; j < 4; ++j) cp[j * 16] = f2bf(acc[i][j][r]);
    }
}

// 8 projection GEMMs in one launch. grid (32, 32)
__global__ __launch_bounds__(256)
void proj_tiled(const unsigned short* __restrict__ XB,
                const unsigned short* __restrict__ SYB,
                const unsigned short* __restrict__ Wcat,
                unsigned short* __restrict__ Qbase,
                unsigned short* __restrict__ SV)
{
  __shared__ unsigned short As[128 * 32];
  __shared__ unsigned short Bs[128 * 32];
  const int m0 = blockIdx.x * 128;
  const int ny = blockIdx.y;
  const size_t NB = (size_t)B_ * S_ * PJ_;
  const unsigned short* A;
  const unsigned short* Wb;
  unsigned short* Cb;
  if (ny < 28) {
    const int n0 = ny * 128;
    A  = XB;
    Wb = Wcat + (size_t)n0 * DM_;
    Cb = Qbase + (size_t)(n0 >> 9) * NB + (size_t)m0 * PJ_ + (n0 & 511);
  } else {
    const int n0 = (ny - 28) * 128;
    A  = SYB;
    Wb = Wcat + (size_t)7 * PJ_ * DM_ + (size_t)n0 * DM_;
    Cb = SV + (size_t)m0 * PJ_ + n0;
  }
  gemm128_glds(A, m0, Wb, Cb, PJ_, DM_, As, Bs);
}

// ---------------------------------------------------------------------------
// Output projections: 128m x 64n tiles (512 blocks). grid (32, 16).
// ---------------------------------------------------------------------------
__global__ __launch_bounds__(256)
void out_tiled(const unsigned short* __restrict__ Asa,
               const unsigned short* __restrict__ Ara,
               const unsigned short* __restrict__ WOSA,
               const unsigned short* __restrict__ WORA,
               float* __restrict__ Out)
{
  __shared__ unsigned short As[128 * 40];
  __shared__ unsigned short Bs[64 * 40];
  const int m0 = blockIdx.x * 128;
  const int ny = blockIdx.y;
  const int n0 = (ny & 7) * 64;
  const unsigned short* A  = (ny < 8) ? Asa : Ara;
  const unsigned short* Wb = ((ny < 8) ? WOSA : WORA) + (size_t)n0 * PJ_;
  float* Cb = Out + (size_t)m0 * DM_ + ((ny < 8) ? 0 : 512) + n0;

  const int tid = threadIdx.x;
  const int wv = tid >> 6, lane = tid & 63;
  const int r15 = lane & 15, quad = lane >> 4;
  const int wm = wv * 32;
  f32x4 acc[2][4];
#pragma unroll
  for (int i = 0; i < 2; ++i)
#pragma unroll
    for (int j = 0; j < 4; ++j) acc[i][j] = (f32x4){0.f, 0.f, 0.f, 0.f};

  const int arow = tid >> 1, ac = (tid & 1) * 16;
  const int brow = tid >> 2, bc = (tid & 3) * 8;
  const unsigned short* ga = A + (size_t)(m0 + arow) * PJ_ + ac;
  const unsigned short* gb = Wb + (size_t)brow * PJ_ + bc;
  unsigned short* la = As + arow * 40 + ac;
  unsigned short* lb = Bs + brow * 40 + bc;

  for (int kk = 0; kk < PJ_; kk += 32) {
    __syncthreads();
    const uint4 a0 = *(const uint4*)(ga + kk);
    const uint4 a1 = *(const uint4*)(ga + kk + 8);
    const uint4 b0 = *(const uint4*)(gb + kk);
    *(uint4*)la       = a0;
    *(uint4*)(la + 8) = a1;
    *(uint4*)lb       = b0;
    __syncthreads();
    bf16x8 af[2], bf[4];
#pragma unroll
    for (int i = 0; i < 2; ++i)
      af[i] = *(const bf16x8*)(As + (wm + i * 16 + r15) * 40 + quad * 8);
#pragma unroll
    for (int j = 0; j < 4; ++j)
      bf[j] = *(const bf16x8*)(Bs + (j * 16 + r15) * 40 + quad * 8);
#pragma unroll
    for (int i = 0; i < 2; ++i)
#pragma unroll
      for (int j = 0; j < 4; ++j)
        acc[i][j] = __builtin_amdgcn_mfma_f32_16x16x32_bf16(af[i], bf[j], acc[i][j], 0, 0, 0);
  }
#pragma unroll
  for (int i = 0; i < 2; ++i)
#pragma unroll
    for (int r = 0; r < 4; ++r) {
      float* cp = Cb + (size_t)(wm + i * 16 + quad * 4 + r) * DM_ + r15;
#pragma unroll
      for (int j = 0; j < 4; ++j) cp[j * 16] = acc[i][j][r];
    }
}

// ---------------------------------------------------------------------------
// rel materialization (tri-128 LDS GEMM), FUSED with vectorized RoPE.
// Tiles stored in B-frag-sigma order so flash_part feeds them DIRECTLY into
// MFMA as the second operand (arp-as-MFMA):
//   flat tile index = sub*1024 + k0*512 + lane*8 + jj  holds
//   rel[i' = sub*16 + (lane&15)][j = ((k0<<1)|(jj>>2))*16 + (lane>>4)*4 + (jj&3)]
// grid (136, 16).
// ---------------------------------------------------------------------------
__global__ __launch_bounds__(256)
void rel_rope(const unsigned short* __restrict__ QRg, const unsigned short* __restrict__ KRg,
              unsigned short* __restrict__ RelCF,
              unsigned short* __restrict__ Qp, unsigned short* __restrict__ Kp,
              unsigned short* __restrict__ QAp, unsigned short* __restrict__ KAp,
              const float* __restrict__ fcp, const float* __restrict__ fsp)
{
  __shared__ unsigned short As[128 * 72];
  __shared__ unsigned short Bs[128 * 72];
  const int t = blockIdx.x;
  int I = 0;
  while ((I + 1) * (I + 2) / 2 <= t) ++I;
  const int J = t - I * (I + 1) / 2;
  const int rr = blockIdx.y & 7, b = blockIdx.y >> 3;
  const int tid = threadIdx.x;
  const int wv = tid >> 6, lane = tid & 63;
  const int r15 = lane & 15, quad = lane >> 4;

  const int srow = tid >> 1, c32 = (tid & 1) * 32;
  const unsigned short* ga = QRg + (size_t)(b * S_ + I * 128 + srow) * PJ_ + rr * 64 + c32;
  const unsigned short* gb = KRg + (size_t)(b * S_ + J * 128 + srow) * PJ_ + rr * 64 + c32;
  unsigned short* la = As + srow * 72 + c32;
  unsigned short* lb = Bs + srow * 72 + c32;
#pragma unroll
  for (int q = 0; q < 4; ++q) {
    *(uint4*)(la + q * 8) = *(const uint4*)(ga + q * 8);
    *(uint4*)(lb + q * 8) = *(const uint4*)(gb + q * 8);
  }
  __syncthreads();

  const int wm = (wv >> 1) * 64, wn = (wv & 1) * 64;
  const int it64 = 2 * I + (wv >> 1), jt64 = 2 * J + (wv & 1);
  if (jt64 <= it64) {
    f32x4 acc[4][4];           // acc[a][b]: a = j-16-block, b = i-16-block
#pragma unroll
    for (int a = 0; a < 4; ++a)
#pragma unroll
      for (int bq = 0; bq < 4; ++bq) acc[a][bq] = (f32x4){0.f, 0.f, 0.f, 0.f};
#pragma unroll
    for (int k0 = 0; k0 < 2; ++k0) {
      bf16x8 af[4], bf[4];
#pragma unroll
      for (int i = 0; i < 4; ++i)
        af[i] = *(const bf16x8*)(As + (wm + i * 16 + r15) * 72 + quad * 8 + k0 * 32);
#pragma unroll
      for (int j = 0; j < 4; ++j)
        bf[j] = *(const bf16x8*)(Bs + (wn + j * 16 + r15) * 72 + quad * 8 + k0 * 32);
#pragma unroll
      for (int a = 0; a < 4; ++a)
#pragma unroll
        for (int bq = 0; bq < 4; ++bq)
          acc[a][bq] = __builtin_amdgcn_mfma_f32_16x16x32_bf16(bf[a], af[bq], acc[a][bq], 0, 0, 0);
    }
    unsigned short* out = RelCF + ((size_t)(b * 8 + rr) * NTRI + (size_t)it64 * (it64 + 1) / 2 + jt64) * 4096;
#pragma unroll
    for (int bq = 0; bq < 4; ++bq) {
      unsigned short tmp[16];
#pragma unroll
      for (int a = 0; a < 4; ++a)
#pragma unroll
        for (int r = 0; r < 4; ++r)
          tmp[a * 4 + r] = f2bf(acc[a][bq][r] * 0.125f);
      unsigned short* op = out + (size_t)bq * 1024 + (size_t)lane * 8;   // k0=0 half
      *(uint4*)op         = *(const uint4*)tmp;
      *(uint4*)(op + 512) = *(const uint4*)(tmp + 8);                    // k0=1 half
    }
  }

  // ---- fused RoPE (all threads): 2 uint4 slices of {Q,K,QA,KA} each ----
  // per-tensor uint4 count = NB/8 = 262144 = 2^18; total = 4*2^18 = 1048576.
  const int bid = (int)blockIdx.y * 136 + (int)blockIdx.x;
  const int gt = bid * 256 + tid;
#pragma unroll
  for (int k = 0; k < 2; ++k) {
    const int i = gt * 2 + k;
    if (i >= 4 * 262144) continue;
    const int tn = i >> 18;
    const int r2 = i & 262143;
    unsigned short* P = (tn == 0) ? Qp : (tn == 1) ? Kp : (tn == 2) ? QAp : KAp;
    const int b2 = r2 >> 17;                  // 131072 uint4 per batch
    const int s2 = (r2 >> 6) & 2047;          // 64 uint4 per 512-wide row
    const int c8 = (r2 & 63) * 8;             // column offset (elements)
    const int ci0 = (c8 & 63) >> 1;           // first rotary index of 4 pairs
    const size_t off2 = ((size_t)(b2 * S_ + s2)) * PJ_ + c8;
    uint4 v = *(const uint4*)(P + off2);
    unsigned int u[4] = {v.x, v.y, v.z, v.w};
    unsigned int o[4];
#pragma unroll
    for (int q = 0; q < 4; ++q) {
      const float xr = __uint_as_float(u[q] << 16);
      const float xi = __uint_as_float(u[q] & 0xffff0000u);
      const float cs = fcp[s2 * 32 + ci0 + q];
      const float sn = fsp[s2 * 32 + ci0 + q];
      const unsigned short lo = f2bf(xr * cs - xi * sn);
      const unsigned short hi = f2bf(xr * sn + xi * cs);
      o[q] = (unsigned int)lo | ((unsigned int)hi << 16);
    }
    uint4 ov; ov.x = o[0]; ov.y = o[1]; ov.z = o[2]; ov.w = o[3];
    *(uint4*)(P + off2) = ov;
  }
}

// ---------------------------------------------------------------------------
// Split-j flash partial pass — r22: EXACT r19 structure restored (measured
// best: 92 µs, VGPR 88, no spill).  A/B evidence from the session:
//  * r18/r1: launch_bounds min-waves clamp -> 64-VGPR tier -> ~600 MB spill
//    traffic (2x regression).  NEVER set the second arg here.
//  * r20: K-direct-from-global -> 8 uncovered dependent loads on the QK
//    critical path (92 -> 143).  K stays LDS-staged.
//  * r21: masked-tile early-return + "pipelined" rel loads -> branchy TILE
//    body defeats compiler load hoisting (92 -> 101).  TILE stays
//    branch-free; rel rr=0..3 prefetched up-front, rr=4..7 loaded in the
//    unrolled loop (compiler batches them).
// Structure: 128-row i-blocks (block a owns i-tiles {2a, 2a+1}), 8 waves,
// KVBLK=128 (2 j-tiles per barrier round), K+V double-buffered in LDS,
// V columns sigma-permuted, arp-as-MFMA against B-frag-sigma rel tiles,
// l via ones-MFMA, cvt_pk P-pack, exp2 softmax.
// grid (40, 16, 2). Partials per chunk: Po bf16 128x64, l f32 128, arp f32 128x8.
// ---------------------------------------------------------------------------
__global__ __launch_bounds__(512)
void flash_part(const unsigned short* __restrict__ Qsa, const unsigned short* __restrict__ Ksa,
                const unsigned short* __restrict__ Vsa,
                const unsigned short* __restrict__ Qra, const unsigned short* __restrict__ Kra,
                const unsigned short* __restrict__ SVra,
                const unsigned short* __restrict__ RelCF,
                unsigned short* __restrict__ PoP, float* __restrict__ lP,
                float* __restrict__ arpP)
{
  __shared__ unsigned short Ks[2][2][64][72];
  __shared__ unsigned short Vt[2][2][64][72];   // [buf][tile][d][kslot]
  const int x = NCHK2 - 1 - (int)blockIdx.x;    // big chunks dispatch first
  int a, c;
  if (x < 4)       { a = x;                 c = 0; }
  else if (x < 12) { a = 4 + ((x - 4) >> 1);  c = (x - 4) & 1; }
  else if (x < 24) { a = 8 + (x - 12) / 3;    c = (x - 12) % 3; }
  else             { a = 12 + ((x - 24) >> 2); c = (x - 24) & 3; }
  const int j0 = c * 8;
  const int jendF = 2 * a + 2;
  const int jend = (j0 + 8 < jendF) ? (j0 + 8) : jendF;   // always even
  const bool ra = (blockIdx.y >= 8);
  const int h = blockIdx.y & 7;
  const int b = blockIdx.z;
  const int chunkId = (b * 16 + (int)blockIdx.y) * NCHK2 + x;
  const unsigned short* Qg = ra ? Qra : Qsa;
  const unsigned short* Kg = ra ? Kra : Ksa;
  const unsigned short* Vg = ra ? SVra : Vsa;
  const int tid = threadIdx.x;
  const int wv = tid >> 6, lane = tid & 63;
  const int r15 = lane & 15, quad = lane >> 4;
  const size_t bh = (size_t)b * S_ * PJ_ + (size_t)h * D_;
  const size_t relStride = (size_t)NTRI * 4096;
  const int it_wave = 2 * a + (wv >> 2);        // wave-uniform
  const int gi = a * 128 + wv * 16 + r15;       // lane's global i-row

  // staging addresses (per-thread constants); 512 threads: one uint4 per tile
  const int kr = tid >> 3, kc0 = (tid & 7) << 3;          // K: row 0..63, col
  const unsigned short* kgp = Kg + bh + (size_t)kr * PJ_ + kc0;
  const unsigned short* vgp = Vg + bh + (size_t)lane * PJ_ + wv * 8;  // V row=lane, d=wv*8..+7
  // sigma^-1: k-slot for this thread's staged V column (j = lane)
  const int kcol = ((lane >> 2) & 3) * 8 + ((lane >> 4) & 1) * 4 + (lane & 3) + (lane >> 5) * 32;

  // Q fragments in registers (layout: row=r15, k=quad*8+j — serves as B-frag)
  const unsigned short* qp = Qg + bh + (size_t)gi * PJ_ + quad * 8;
  const bf16x8 aq0 = *(const bf16x8*)qp;
  const bf16x8 aq1 = *(const bf16x8*)(qp + 32);

  const bf16x8 ones = (bf16x8)(short)0x3F80;   // bf16 1.0 splat (B-frag for l)

  f32x4 o_acc[4];
  f32x4 l_acc = (f32x4){0.f, 0.f, 0.f, 0.f};
  f32x4 accR[8];                               // arp MFMA accumulators (ra only)
#pragma unroll
  for (int n = 0; n < 4; ++n) o_acc[n] = (f32x4){0.f, 0.f, 0.f, 0.f};
#pragma unroll
  for (int rr = 0; rr < 8; ++rr) accR[rr] = (f32x4){0.f, 0.f, 0.f, 0.f};
  // B-frag-sigma rel tile base for this wave's 64-tile row (it_wave)
  const size_t relTileBase = (size_t)(b * 8) * NTRI * 4096
                           + (size_t)(it_wave * (it_wave + 1)) / 2 * 4096
                           + (size_t)(wv & 3) * 1024 + (size_t)lane * 8;

  // one j-tile's QK/softmax/l/arp/PV from buffer slot (KsT, VtT)
  auto TILE = [&](int jtt, const unsigned short (*KsT)[72], const unsigned short (*VtT)[72]) {
    const bool dorel = ra && (jtt <= it_wave);
    const unsigned short* rtBase = RelCF + relTileBase + (size_t)jtt * 4096;
    uint4 pre[8];
    if (dorel) {
      const unsigned short* rt = rtBase;
#pragma unroll
      for (int q = 0; q < 4; ++q) {
        pre[2 * q]     = *(const uint4*)rt;
        pre[2 * q + 1] = *(const uint4*)(rt + 512);
        rt += relStride;
      }
    }
    // QK^T, SWAPPED operands: lane row i=gi, j = jtt*64 + n*16 + quad*4 + r
    f32x4 s[4];
#pragma unroll
    for (int n = 0; n < 4; ++n) s[n] = (f32x4){0.f, 0.f, 0.f, 0.f};
#pragma unroll
    for (int k0 = 0; k0 < 2; ++k0) {
      const bf16x8 bq = k0 ? aq1 : aq0;
#pragma unroll
      for (int n = 0; n < 4; ++n) {
        const bf16x8 kf = *(const bf16x8*)&KsT[n * 16 + r15][quad * 8 + k0 * 32];
        s[n] = __builtin_amdgcn_mfma_f32_16x16x32_bf16(kf, bq, s[n], 0, 0, 0);
      }
    }
    // fixed-shift softmax: exp(s*0.125-4) = exp2(fma(s, log2e/8, -4log2e))
    if (jtt >= it_wave) {   // diagonal or fully-masked tile
#pragma unroll
      for (int n = 0; n < 4; ++n)
#pragma unroll
        for (int r = 0; r < 4; ++r) {
          const bool ok = (jtt * 64 + n * 16 + quad * 4 + r <= gi);
          s[n][r] = ok ? exp2f(fmaf(s[n][r], 0.180336887f, -5.770780163f)) : 0.f;
        }
    } else {
#pragma unroll
      for (int n = 0; n < 4; ++n)
#pragma unroll
        for (int r = 0; r < 4; ++r)
          s[n][r] = exp2f(fmaf(s[n][r], 0.180336887f, -5.770780163f));
    }
    // packed P->bf16 under sigma
    uint4 w0, w1;
    w0.x = cvtpk_bf16(s[0][0], s[0][1]); w0.y = cvtpk_bf16(s[0][2], s[0][3]);
    w0.z = cvtpk_bf16(s[1][0], s[1][1]); w0.w = cvtpk_bf16(s[1][2], s[1][3]);
    w1.x = cvtpk_bf16(s[2][0], s[2][1]); w1.y = cvtpk_bf16(s[2][2], s[2][3]);
    w1.z = cvtpk_bf16(s[3][0], s[3][1]); w1.w = cvtpk_bf16(s[3][2], s[3][3]);
    const bf16x8 pa0 = u4_to_bf(w0);
    const bf16x8 pa1 = u4_to_bf(w1);
    // l via MFMA against constant ones B-frag
    l_acc = __builtin_amdgcn_mfma_f32_16x16x32_bf16(pa0, ones, l_acc, 0, 0, 0);
    l_acc = __builtin_amdgcn_mfma_f32_16x16x32_bf16(pa1, ones, l_acc, 0, 0, 0);
    // arp MFMAs rr=0..3 (diag of D = arp)
    if (dorel) {
#pragma unroll
      for (int rr = 0; rr < 4; ++rr) {
        accR[rr] = __builtin_amdgcn_mfma_f32_16x16x32_bf16(pa0, u4_to_bf(pre[2 * rr]), accR[rr], 0, 0, 0);
        accR[rr] = __builtin_amdgcn_mfma_f32_16x16x32_bf16(pa1, u4_to_bf(pre[2 * rr + 1]), accR[rr], 0, 0, 0);
      }
    }
    // PV: 8 MFMAs (Vt columns are sigma-permuted)
#pragma unroll
    for (int k0 = 0; k0 < 2; ++k0) {
      const bf16x8 pf = k0 ? pa1 : pa0;
#pragma unroll
      for (int n = 0; n < 4; ++n) {
        const bf16x8 vf = *(const bf16x8*)&VtT[n * 16 + r15][quad * 8 + k0 * 32];
        o_acc[n] = __builtin_amdgcn_mfma_f32_16x16x32_bf16(pf, vf, o_acc[n], 0, 0, 0);
      }
    }
    // arp MFMAs rr=4..7
    if (dorel) {
      const unsigned short* rt2 = rtBase + 4 * relStride;
#pragma unroll
      for (int rr = 4; rr < 8; ++rr) {
        const bf16x8 rb0 = *(const bf16x8*)rt2;
        const bf16x8 rb1 = *(const bf16x8*)(rt2 + 512);
        accR[rr] = __builtin_amdgcn_mfma_f32_16x16x32_bf16(pa0, rb0, accR[rr], 0, 0, 0);
        accR[rr] = __builtin_amdgcn_mfma_f32_16x16x32_bf16(pa1, rb1, accR[rr], 0, 0, 0);
        rt2 += relStride;
      }
    }
  };

  // prologue: load round (j0, j0+1), store to buf 0
  uint4 ka0, ka1, va0, va1;
  {
    const size_t jb0 = (size_t)j0 * 64 * PJ_;
    const size_t jb1 = (size_t)(j0 + 1) * 64 * PJ_;
    ka0 = *(const uint4*)(kgp + jb0);
    ka1 = *(const uint4*)(kgp + jb1);
    va0 = *(const uint4*)(vgp + jb0);
    va1 = *(const uint4*)(vgp + jb1);
  }
  int p = 0;
  {
    *(uint4*)&Ks[0][0][kr][kc0] = ka0;
    *(uint4*)&Ks[0][1][kr][kc0] = ka1;
    unsigned short t8[8];
    *(uint4*)t8 = va0;
#pragma unroll
    for (int m = 0; m < 8; ++m) Vt[0][0][wv * 8 + m][kcol] = t8[m];
    *(uint4*)t8 = va1;
#pragma unroll
    for (int m = 0; m < 8; ++m) Vt[0][1][wv * 8 + m][kcol] = t8[m];
  }
  __syncthreads();

  for (int jt = j0; jt < jend; jt += 2) {
    const bool more = (jt + 2 < jend);
    if (more) {   // issue next round's loads (2 tiles of compute to hide)
      const size_t jb0 = (size_t)(jt + 2) * 64 * PJ_;
      const size_t jb1 = (size_t)(jt + 3) * 64 * PJ_;
      ka0 = *(const uint4*)(kgp + jb0);
      ka1 = *(const uint4*)(kgp + jb1);
      va0 = *(const uint4*)(vgp + jb0);
      va1 = *(const uint4*)(vgp + jb1);
    }
    TILE(jt,     Ks[p][0], Vt[p][0]);
    TILE(jt + 1, Ks[p][1], Vt[p][1]);
    if (more) {
      const int q = p ^ 1;
      *(uint4*)&Ks[q][0][kr][kc0] = ka0;
      *(uint4*)&Ks[q][1][kr][kc0] = ka1;
      unsigned short t8[8];
      *(uint4*)t8 = va0;
#pragma unroll
      for (int m = 0; m < 8; ++m) Vt[q][0][wv * 8 + m][kcol] = t8[m];
      *(uint4*)t8 = va1;
#pragma unroll
      for (int m = 0; m < 8; ++m) Vt[q][1][wv * 8 + m][kcol] = t8[m];
      __syncthreads();
      p = q;
    }
  }
  // ---- write partials (chunk: Po 128x64, l 128, arp 128x8) ----
  unsigned short* po = PoP + (size_t)chunkId * 8192;
#pragma unroll
  for (int n = 0; n < 4; ++n)
#pragma unroll
    for (int r = 0; r < 4; ++r)
      po[(wv * 16 + quad * 4 + r) * 64 + n * 16 + r15] = f2bf(o_acc[n][r]);
  if (r15 == 0) {
#pragma unroll
    for (int r = 0; r < 4; ++r)
      lP[(size_t)chunkId * 128 + wv * 16 + quad * 4 + r] = l_acc[r];
  }
  // arp: diagonal lanes (quad == r15>>2) hold the full j-sum in comp r15&3
  if (ra && quad == (r15 >> 2)) {
    const int d3 = r15 & 3;
    float* ap = arpP + (size_t)chunkId * 1024 + (size_t)(wv * 16 + r15) * 8;
#pragma unroll
    for (int rr = 0; rr < 8; ++rr) {
      const f32x4 a4 = accR[rr];
      const float v = (d3 == 0) ? a4[0] : (d3 == 1) ? a4[1] : (d3 == 2) ? a4[2] : a4[3];
      ap[rr] = v;
    }
  }
}

// ---------------------------------------------------------------------------
// Merge split-j partials (pure sums) + wr (f32) epilogue. grid (32, 16, 2).
// Chunks are 128-row i-blocks; tile it -> block a = it>>1, half = it&1.
// ---------------------------------------------------------------------------
__global__ __launch_bounds__(256)
void flash_merge(const unsigned short* __restrict__ PoP, const float* __restrict__ lP,
                 const float* __restrict__ arpP, const float* __restrict__ wrF,
                 unsigned short* __restrict__ Osa, unsigned short* __restrict__ Ora)
{
  const int it = blockIdx.x;
  const int hh = blockIdx.y;
  const int b  = blockIdx.z;
  const bool ra = (hh >= 8);
  const int h = hh & 7;
  const int a  = it >> 1;
  const int half = it & 1;
  const int nc = ((2 * a + 1) >> 3) + 1;
  int cb;
  if (a < 4)       cb = a;
  else if (a < 8)  cb = 4 + 2 * (a - 4);
  else if (a < 12) cb = 12 + 3 * (a - 8);
  else             cb = 24 + 4 * (a - 12);
  const int cid0 = (b * 16 + hh) * NCHK2 + cb;
  const int tid = threadIdx.x;
  const int row = tid >> 2;            // 0..63 within this 64-row half
  const int cg  = tid & 3;
  const int prow = half * 64 + row;    // row within the 128-row chunk

  float L = 0.f;
  for (int c = 0; c < nc; ++c) L += lP[(size_t)(cid0 + c) * 128 + prow];
  const float inv = 1.f / L;

  float o[16];
#pragma unroll
  for (int k = 0; k < 16; ++k) o[k] = 0.f;
  for (int c = 0; c < nc; ++c) {
    const unsigned short* pp = PoP + (size_t)(cid0 + c) * 8192 + prow * 64 + cg * 16;
    unsigned int u[8];
    *(uint4*)u       = *(const uint4*)pp;
    *(uint4*)(u + 4) = *(const uint4*)(pp + 8);
#pragma unroll
    for (int q = 0; q < 8; ++q) {
      o[2 * q]     += __uint_as_float(u[q] << 16);
      o[2 * q + 1] += __uint_as_float(u[q] & 0xffff0000u);
    }
  }
  if (ra) {
    float A[8];
#pragma unroll
    for (int rr = 0; rr < 8; ++rr) A[rr] = 0.f;
    for (int c = 0; c < nc; ++c) {
      const float* ap = arpP + (size_t)(cid0 + c) * 1024 + (size_t)prow * 8;
#pragma unroll
      for (int rr = 0; rr < 8; ++rr) A[rr] += ap[rr];
    }
#pragma unroll
    for (int k = 0; k < 16; ++k) {
      const float* wp = wrF + ((size_t)h * 64 + cg * 16 + k) * 8;
      float ro = 0.f;
#pragma unroll
      for (int rr = 0; rr < 8; ++rr) ro += A[rr] * wp[rr];
      o[k] += ro;
    }
  }
  const size_t bh = (size_t)b * S_ * PJ_ + (size_t)h * D_;
  unsigned short* op = (ra ? Ora : Osa) + bh + (size_t)(it * 64 + row) * PJ_ + cg * 16;
#pragma unroll
  for (int k = 0; k < 16; ++k) op[k] = f2bf(o[k] * inv);
}

// ---------------------------------------------------------------------------
extern "C" void kernel_launch(void* const* d_in, const int* in_sizes, int n_in,
                              void* d_out, int out_size, void* d_ws, size_t ws_size,
                              hipStream_t stream)
{
  (void)in_sizes; (void)n_in; (void)out_size; (void)ws_size;
  const float* x    = (const float*)d_in[0];
  const float* sym  = (const float*)d_in[1];
  const float* fc   = (const float*)d_in[2];
  const float* fs   = (const float*)d_in[3];
  const float* wqsa = (const float*)d_in[4];
  const float* wksa = (const float*)d_in[5];
  const float* wvsa = (const float*)d_in[6];
  const float* wosa = (const float*)d_in[7];
  const float* wqat = (const float*)d_in[8];
  const float* wkat = (const float*)d_in[9];
  const float* wqre = (const float*)d_in[10];
  const float* wkre = (const float*)d_in[11];
  const float* wr   = (const float*)d_in[12];
  const float* wvra = (const float*)d_in[13];
  const float* wora = (const float*)d_in[14];

  unsigned short* wsb = (unsigned short*)d_ws;
  const size_t NX = (size_t)B_ * S_ * DM_;
  const size_t NB = (size_t)B_ * S_ * PJ_;
  const size_t NW = (size_t)PJ_ * DM_;
  const size_t NO = (size_t)PJ_ * PJ_;
  const size_t NR = (size_t)B_ * 8 * NTRI * 4096;
  const size_t NCH = (size_t)B_ * 16 * NCHK2;   // 1280 chunks

  size_t off = 0;
  unsigned short* XB   = wsb + off; off += NX;
  unsigned short* SYB  = wsb + off; off += NX;
  unsigned short* WB[8];
  for (int i = 0; i < 8; ++i) { WB[i] = wsb + off; off += NW; }
  unsigned short* WOSA = wsb + off; off += NO;
  unsigned short* WORA = wsb + off; off += NO;
  unsigned short* Q    = wsb + off; off += NB;
  unsigned short* K    = wsb + off; off += NB;
  unsigned short* V    = wsb + off; off += NB;
  unsigned short* QA   = wsb + off; off += NB;
  unsigned short* KA   = wsb + off; off += NB;
  unsigned short* QR   = wsb + off; off += NB;
  unsigned short* KR   = wsb + off; off += NB;
  unsigned short* SV   = wsb + off; off += NB;
  unsigned short* Asa  = wsb + off; off += NB;
  unsigned short* Ara  = wsb + off; off += NB;
  unsigned short* RelCF = wsb + off; off += NR;
  unsigned short* PoP  = XB;                      // aliases dead XB/SYB/WB[0..3]
  float* lP   = (float*)(wsb + off); off += NCH * 128 * 2;
  float* arpP = (float*)(wsb + off); off += NCH * 1024 * 2;

  CvtJobs cj;
  cj.src[0]  = x;    cj.dst[0]  = XB;    cj.n4[0]  = (int)(NX / 4);
  cj.src[1]  = sym;  cj.dst[1]  = SYB;   cj.n4[1]  = (int)(NX / 4);
  cj.src[2]  = wqsa; cj.dst[2]  = WB[0]; cj.n4[2]  = (int)(NW / 4);
  cj.src[3]  = wksa; cj.dst[3]  = WB[1]; cj.n4[3]  = (int)(NW / 4);
  cj.src[4]  = wvsa; cj.dst[4]  = WB[2]; cj.n4[4]  = (int)(NW / 4);
  cj.src[5]  = wqat; cj.dst[5]  = WB[3]; cj.n4[5]  = (int)(NW / 4);
  cj.src[6]  = wkat; cj.dst[6]  = WB[4]; cj.n4[6]  = (int)(NW / 4);
  cj.src[7]  = wqre; cj.dst[7]  = WB[5]; cj.n4[7]  = (int)(NW / 4);
  cj.src[8]  = wkre; cj.dst[8]  = WB[6]; cj.n4[8]  = (int)(NW / 4);
  cj.src[9]  = wvra; cj.dst[9]  = WB[7]; cj.n4[9]  = (int)(NW / 4);
  cj.src[10] = wosa; cj.dst[10] = WOSA;  cj.n4[10] = (int)(NO / 4);
  cj.src[11] = wora; cj.dst[11] = WORA;  cj.n4[11] = (int)(NO / 4);
  cvt_many<<<dim3(4096, 12), dim3(256), 0, stream>>>(cj);

  proj_tiled<<<dim3(32, 32), dim3(256), 0, stream>>>(XB, SYB, WB[0], Q, SV);
  rel_rope<<<dim3(136, 16), dim3(256), 0, stream>>>(QR, KR, RelCF, Q, K, QA, KA, fc, fs);
  flash_part<<<dim3(NCHK2, 16, B_), dim3(512), 0, stream>>>(
      Q, K, V, QA, KA, SV, RelCF, PoP, lP, arpP);
  flash_merge<<<dim3(NT_, 16, B_), dim3(256), 0, stream>>>(
      PoP, lP, arpP, wr, Asa, Ara);
  out_tiled<<<dim3(32, 16), dim3(256), 0, stream>>>(Asa, Ara, WOSA, WORA, (float*)d_out);
}

// Round 9
// 298.515 us; speedup vs baseline: 1.1842x; 1.0099x over previous
//
#include <hip/hip_runtime.h>

#define B_   2
#define S_   2048
#define H_   8
#define D_   64
#define DM_  1024
#define PJ_  512          // H_*D_ = projection width
#define NT_  32           // S_/64 i-tiles
#define NTRI 528          // NT_*(NT_+1)/2 lower-triangular 64-tiles
#define NCHK2 40          // split-j chunks per (b,hh) over 128-row i-blocks

typedef short bf16x8 __attribute__((ext_vector_type(8)));
typedef float f32x4 __attribute__((ext_vector_type(4)));

__device__ __forceinline__ float bf2f(unsigned int u) {
  return __uint_as_float(u << 16);
}
__device__ __forceinline__ unsigned short f2bf(float f) {
  unsigned int u = __float_as_uint(f);
  u += 0x7fffu + ((u >> 16) & 1u);           // round-to-nearest-even
  return (unsigned short)(u >> 16);
}
// packed f32x2 -> bf16x2 (RNE), gfx950 has no builtin (T12) — inline asm
__device__ __forceinline__ unsigned int cvtpk_bf16(float lo, float hi) {
  unsigned int r;
  asm("v_cvt_pk_bf16_f32 %0, %1, %2" : "=v"(r) : "v"(lo), "v"(hi));
  return r;
}
__device__ __forceinline__ bf16x8 u4_to_bf(uint4 v) {
  union { uint4 a; bf16x8 b; } u; u.a = v; return u.b;
}

// async global->LDS DMA, 16 B/lane; LDS dest = wave-uniform base + lane*16
__device__ __forceinline__ void glds16(const unsigned short* g, unsigned short* l) {
  __builtin_amdgcn_global_load_lds(
      (const __attribute__((address_space(1))) void*)g,
      (__attribute__((address_space(3))) void*)l, 16, 0, 0);
}

// ---------------------------------------------------------------------------
// f32 -> bf16 conversion (12 jobs; wr stays f32 and is read directly).
// ---------------------------------------------------------------------------
struct CvtJobs {
  const float*    src[12];
  unsigned short* dst[12];
  int             n4[12];
};

__global__ __launch_bounds__(256) void cvt_many(CvtJobs J) {
  const int j = blockIdx.y;
  const int i = blockIdx.x * 256 + threadIdx.x;
  if (i >= J.n4[j]) return;
  const float4 v = ((const float4*)J.src[j])[i];
  ushort4 o;
  o.x = f2bf(v.x); o.y = f2bf(v.y); o.z = f2bf(v.z); o.w = f2bf(v.w);
  ((ushort4*)J.dst[j])[i] = o;
}

// ---------------------------------------------------------------------------
// 128x128-tile MFMA GEMM with global_load_lds staging (m97 ladder step).
// ---------------------------------------------------------------------------
__device__ __forceinline__
void gemm128_glds(const unsigned short* __restrict__ A, int m0,
                  const unsigned short* __restrict__ Wb,
                  unsigned short* __restrict__ Cb, int ldc, int KD,
                  unsigned short* As, unsigned short* Bs)
{
  const int tid = threadIdx.x;
  const int wv = tid >> 6, lane = tid & 63;
  const int r15 = lane & 15, quad = lane >> 4;
  const int wm = (wv >> 1) * 64, wn = (wv & 1) * 64;
  f32x4 acc[4][4];
#pragma unroll
  for (int i = 0; i < 4; ++i)
#pragma unroll
    for (int j = 0; j < 4; ++j) acc[i][j] = (f32x4){0.f, 0.f, 0.f, 0.f};

  const int srow = wv * 16 + (lane >> 2);
  const int scol = ((lane & 3) ^ ((lane >> 3) & 3)) * 8;   // xor-swizzled source col
  const unsigned short* gaA0 = A + (size_t)(m0 + srow) * KD + scol;
  const unsigned short* gaA1 = gaA0 + (size_t)64 * KD;
  const unsigned short* gaB0 = Wb + (size_t)srow * KD + scol;
  const unsigned short* gaB1 = gaB0 + (size_t)64 * KD;
  unsigned short* ldsA0 = As + wv * 512;
  unsigned short* ldsA1 = As + 2048 + wv * 512;
  unsigned short* ldsB0 = Bs + wv * 512;
  unsigned short* ldsB1 = Bs + 2048 + wv * 512;
  const int rxor = (r15 >> 1) & 3;                         // read-side xor

  for (int kk = 0; kk < KD; kk += 32) {
    __syncthreads();
    glds16(gaA0 + kk, ldsA0);
    glds16(gaA1 + kk, ldsA1);
    glds16(gaB0 + kk, ldsB0);
    glds16(gaB1 + kk, ldsB1);
    __syncthreads();     // drains vmcnt for the DMA
    bf16x8 af[4], bf[4];
#pragma unroll
    for (int i = 0; i < 4; ++i)
      af[i] = *(const bf16x8*)(As + (wm + i * 16 + r15) * 32 + ((quad ^ rxor) << 3));
#pragma unroll
    for (int j = 0; j < 4; ++j)
      bf[j] = *(const bf16x8*)(Bs + (wn + j * 16 + r15) * 32 + ((quad ^ rxor) << 3));
#pragma unroll
    for (int i = 0; i < 4; ++i)
#pragma unroll
      for (int j = 0; j < 4; ++j)
        acc[i][j] = __builtin_amdgcn_mfma_f32_16x16x32_bf16(af[i], bf[j], acc[i][j], 0, 0, 0);
  }
#pragma unroll
  for (int i = 0; i < 4; ++i)
#pragma unroll
    for (int r = 0; r < 4; ++r) {
      unsigned short* cp = Cb + (size_t)(wm + i * 16 + quad * 4 + r) * ldc + wn + r15;
#pragma unroll
      for (int j = 0; j < 4; ++j) cp[j * 16] = f2bf(acc[i][j][r]);
    }
}

// 8 projection GEMMs in one launch. grid (32, 32)
__global__ __launch_bounds__(256)
void proj_tiled(const unsigned short* __restrict__ XB,
                const unsigned short* __restrict__ SYB,
                const unsigned short* __restrict__ Wcat,
                unsigned short* __restrict__ Qbase,
                unsigned short* __restrict__ SV)
{
  __shared__ unsigned short As[128 * 32];
  __shared__ unsigned short Bs[128 * 32];
  const int m0 = blockIdx.x * 128;
  const int ny = blockIdx.y;
  const size_t NB = (size_t)B_ * S_ * PJ_;
  const unsigned short* A;
  const unsigned short* Wb;
  unsigned short* Cb;
  if (ny < 28) {
    const int n0 = ny * 128;
    A  = XB;
    Wb = Wcat + (size_t)n0 * DM_;
    Cb = Qbase + (size_t)(n0 >> 9) * NB + (size_t)m0 * PJ_ + (n0 & 511);
  } else {
    const int n0 = (ny - 28) * 128;
    A  = SYB;
    Wb = Wcat + (size_t)7 * PJ_ * DM_ + (size_t)n0 * DM_;
    Cb = SV + (size_t)m0 * PJ_ + n0;
  }
  gemm128_glds(A, m0, Wb, Cb, PJ_, DM_, As, Bs);
}

// ---------------------------------------------------------------------------
// Output projections: 128m x 64n tiles (512 blocks). grid (32, 16).
// ---------------------------------------------------------------------------
__global__ __launch_bounds__(256)
void out_tiled(const unsigned short* __restrict__ Asa,
               const unsigned short* __restrict__ Ara,
               const unsigned short* __restrict__ WOSA,
               const unsigned short* __restrict__ WORA,
               float* __restrict__ Out)
{
  __shared__ unsigned short As[128 * 40];
  __shared__ unsigned short Bs[64 * 40];
  const int m0 = blockIdx.x * 128;
  const int ny = blockIdx.y;
  const int n0 = (ny & 7) * 64;
  const unsigned short* A  = (ny < 8) ? Asa : Ara;
  const unsigned short* Wb = ((ny < 8) ? WOSA : WORA) + (size_t)n0 * PJ_;
  float* Cb = Out + (size_t)m0 * DM_ + ((ny < 8) ? 0 : 512) + n0;

  const int tid = threadIdx.x;
  const int wv = tid >> 6, lane = tid & 63;
  const int r15 = lane & 15, quad = lane >> 4;
  const int wm = wv * 32;
  f32x4 acc[2][4];
#pragma unroll
  for (int i = 0; i < 2; ++i)
#pragma unroll
    for (int j = 0; j < 4; ++j) acc[i][j] = (f32x4){0.f, 0.f, 0.f, 0.f};

  const int arow = tid >> 1, ac = (tid & 1) * 16;
  const int brow = tid >> 2, bc = (tid & 3) * 8;
  const unsigned short* ga = A + (size_t)(m0 + arow) * PJ_ + ac;
  const unsigned short* gb = Wb + (size_t)brow * PJ_ + bc;
  unsigned short* la = As + arow * 40 + ac;
  unsigned short* lb = Bs + brow * 40 + bc;

  for (int kk = 0; kk < PJ_; kk += 32) {
    __syncthreads();
    const uint4 a0 = *(const uint4*)(ga + kk);
    const uint4 a1 = *(const uint4*)(ga + kk + 8);
    const uint4 b0 = *(const uint4*)(gb + kk);
    *(uint4*)la       = a0;
    *(uint4*)(la + 8) = a1;
    *(uint4*)lb       = b0;
    __syncthreads();
    bf16x8 af[2], bf[4];
#pragma unroll
    for (int i = 0; i < 2; ++i)
      af[i] = *(const bf16x8*)(As + (wm + i * 16 + r15) * 40 + quad * 8);
#pragma unroll
    for (int j = 0; j < 4; ++j)
      bf[j] = *(const bf16x8*)(Bs + (j * 16 + r15) * 40 + quad * 8);
#pragma unroll
    for (int i = 0; i < 2; ++i)
#pragma unroll
      for (int j = 0; j < 4; ++j)
        acc[i][j] = __builtin_amdgcn_mfma_f32_16x16x32_bf16(af[i], bf[j], acc[i][j], 0, 0, 0);
  }
#pragma unroll
  for (int i = 0; i < 2; ++i)
#pragma unroll
    for (int r = 0; r < 4; ++r) {
      float* cp = Cb + (size_t)(wm + i * 16 + quad * 4 + r) * DM_ + r15;
#pragma unroll
      for (int j = 0; j < 4; ++j) cp[j * 16] = acc[i][j][r];
    }
}

// ---------------------------------------------------------------------------
// rel materialization (tri-128 LDS GEMM), FUSED with vectorized RoPE.
// Tiles stored in B-frag-sigma order so flash_part feeds them DIRECTLY into
// MFMA as the second operand (arp-as-MFMA):
//   flat tile index = sub*1024 + k0*512 + lane*8 + jj  holds
//   rel[i' = sub*16 + (lane&15)][j = ((k0<<1)|(jj>>2))*16 + (lane>>4)*4 + (jj&3)]
// grid (136, 16).
// ---------------------------------------------------------------------------
__global__ __launch_bounds__(256)
void rel_rope(const unsigned short* __restrict__ QRg, const unsigned short* __restrict__ KRg,
              unsigned short* __restrict__ RelCF,
              unsigned short* __restrict__ Qp, unsigned short* __restrict__ Kp,
              unsigned short* __restrict__ QAp, unsigned short* __restrict__ KAp,
              const float* __restrict__ fcp, const float* __restrict__ fsp)
{
  __shared__ unsigned short As[128 * 72];
  __shared__ unsigned short Bs[128 * 72];
  const int t = blockIdx.x;
  int I = 0;
  while ((I + 1) * (I + 2) / 2 <= t) ++I;
  const int J = t - I * (I + 1) / 2;
  const int rr = blockIdx.y & 7, b = blockIdx.y >> 3;
  const int tid = threadIdx.x;
  const int wv = tid >> 6, lane = tid & 63;
  const int r15 = lane & 15, quad = lane >> 4;

  const int srow = tid >> 1, c32 = (tid & 1) * 32;
  const unsigned short* ga = QRg + (size_t)(b * S_ + I * 128 + srow) * PJ_ + rr * 64 + c32;
  const unsigned short* gb = KRg + (size_t)(b * S_ + J * 128 + srow) * PJ_ + rr * 64 + c32;
  unsigned short* la = As + srow * 72 + c32;
  unsigned short* lb = Bs + srow * 72 + c32;
#pragma unroll
  for (int q = 0; q < 4; ++q) {
    *(uint4*)(la + q * 8) = *(const uint4*)(ga + q * 8);
    *(uint4*)(lb + q * 8) = *(const uint4*)(gb + q * 8);
  }
  __syncthreads();

  const int wm = (wv >> 1) * 64, wn = (wv & 1) * 64;
  const int it64 = 2 * I + (wv >> 1), jt64 = 2 * J + (wv & 1);
  if (jt64 <= it64) {
    f32x4 acc[4][4];           // acc[a][b]: a = j-16-block, b = i-16-block
#pragma unroll
    for (int a = 0; a < 4; ++a)
#pragma unroll
      for (int bq = 0; bq < 4; ++bq) acc[a][bq] = (f32x4){0.f, 0.f, 0.f, 0.f};
#pragma unroll
    for (int k0 = 0; k0 < 2; ++k0) {
      bf16x8 af[4], bf[4];
#pragma unroll
      for (int i = 0; i < 4; ++i)
        af[i] = *(const bf16x8*)(As + (wm + i * 16 + r15) * 72 + quad * 8 + k0 * 32);
#pragma unroll
      for (int j = 0; j < 4; ++j)
        bf[j] = *(const bf16x8*)(Bs + (wn + j * 16 + r15) * 72 + quad * 8 + k0 * 32);
#pragma unroll
      for (int a = 0; a < 4; ++a)
#pragma unroll
        for (int bq = 0; bq < 4; ++bq)
          acc[a][bq] = __builtin_amdgcn_mfma_f32_16x16x32_bf16(bf[a], af[bq], acc[a][bq], 0, 0, 0);
    }
    unsigned short* out = RelCF + ((size_t)(b * 8 + rr) * NTRI + (size_t)it64 * (it64 + 1) / 2 + jt64) * 4096;
#pragma unroll
    for (int bq = 0; bq < 4; ++bq) {
      unsigned short tmp[16];
#pragma unroll
      for (int a = 0; a < 4; ++a)
#pragma unroll
        for (int r = 0; r < 4; ++r)
          tmp[a * 4 + r] = f2bf(acc[a][bq][r] * 0.125f);
      unsigned short* op = out + (size_t)bq * 1024 + (size_t)lane * 8;   // k0=0 half
      *(uint4*)op         = *(const uint4*)tmp;
      *(uint4*)(op + 512) = *(const uint4*)(tmp + 8);                    // k0=1 half
    }
  }

  // ---- fused RoPE (all threads): 2 uint4 slices of {Q,K,QA,KA} each ----
  // per-tensor uint4 count = NB/8 = 262144 = 2^18; total = 4*2^18 = 1048576.
  const int bid = (int)blockIdx.y * 136 + (int)blockIdx.x;
  const int gt = bid * 256 + tid;
#pragma unroll
  for (int k = 0; k < 2; ++k) {
    const int i = gt * 2 + k;
    if (i >= 4 * 262144) continue;
    const int tn = i >> 18;
    const int r2 = i & 262143;
    unsigned short* P = (tn == 0) ? Qp : (tn == 1) ? Kp : (tn == 2) ? QAp : KAp;
    const int b2 = r2 >> 17;                  // 131072 uint4 per batch
    const int s2 = (r2 >> 6) & 2047;          // 64 uint4 per 512-wide row
    const int c8 = (r2 & 63) * 8;             // column offset (elements)
    const int ci0 = (c8 & 63) >> 1;           // first rotary index of 4 pairs
    const size_t off2 = ((size_t)(b2 * S_ + s2)) * PJ_ + c8;
    uint4 v = *(const uint4*)(P + off2);
    unsigned int u[4] = {v.x, v.y, v.z, v.w};
    unsigned int o[4];
#pragma unroll
    for (int q = 0; q < 4; ++q) {
      const float xr = __uint_as_float(u[q] << 16);
      const float xi = __uint_as_float(u[q] & 0xffff0000u);
      const float cs = fcp[s2 * 32 + ci0 + q];
      const float sn = fsp[s2 * 32 + ci0 + q];
      const unsigned short lo = f2bf(xr * cs - xi * sn);
      const unsigned short hi = f2bf(xr * sn + xi * cs);
      o[q] = (unsigned int)lo | ((unsigned int)hi << 16);
    }
    uint4 ov; ov.x = o[0]; ov.y = o[1]; ov.z = o[2]; ov.w = o[3];
    *(uint4*)(P + off2) = ov;
  }
}

// ---------------------------------------------------------------------------
// Split-j flash partial pass — r23: r22 (= r19) structure with ONE change:
// ALL 16 rel uint4 loads (rr=0..7, both k0 halves) are prefetched into
// pre[16] at TILE start, instead of rr=4..7 being loaded after the PV MFMAs
// and consumed immediately.  Mechanism (T14 issue-early/consume-late): the
// rr=4..7 loads were the only uncovered L3 round-trips in the ra path
// (~300-500 cyc exposed vs ~125 cyc of covering MFMA); moving their issue
// point ~30 MFMAs earlier puts QK+softmax+PV latency in front of the wait.
// +~24 live VGPR (88 -> ~112), still inside the 128 tier -> same residency.
// Session A/B ledger (do not revisit):
//  * launch_bounds min-waves arg -> 64-VGPR clamp + ~600 MB spill (r1/r18).
//  * K-direct-from-global -> uncovered QK-critical loads, 92->143 (r20).
//  * masked-tile early-return / serialized rel pipeline -> 92->101 (r21).
// grid (40, 16, 2). Partials per chunk: Po bf16 128x64, l f32 128, arp f32 128x8.
// ---------------------------------------------------------------------------
__global__ __launch_bounds__(512)
void flash_part(const unsigned short* __restrict__ Qsa, const unsigned short* __restrict__ Ksa,
                const unsigned short* __restrict__ Vsa,
                const unsigned short* __restrict__ Qra, const unsigned short* __restrict__ Kra,
                const unsigned short* __restrict__ SVra,
                const unsigned short* __restrict__ RelCF,
                unsigned short* __restrict__ PoP, float* __restrict__ lP,
                float* __restrict__ arpP)
{
  __shared__ unsigned short Ks[2][2][64][72];
  __shared__ unsigned short Vt[2][2][64][72];   // [buf][tile][d][kslot]
  const int x = NCHK2 - 1 - (int)blockIdx.x;    // big chunks dispatch first
  int a, c;
  if (x < 4)       { a = x;                 c = 0; }
  else if (x < 12) { a = 4 + ((x - 4) >> 1);  c = (x - 4) & 1; }
  else if (x < 24) { a = 8 + (x - 12) / 3;    c = (x - 12) % 3; }
  else             { a = 12 + ((x - 24) >> 2); c = (x - 24) & 3; }
  const int j0 = c * 8;
  const int jendF = 2 * a + 2;
  const int jend = (j0 + 8 < jendF) ? (j0 + 8) : jendF;   // always even
  const bool ra = (blockIdx.y >= 8);
  const int h = blockIdx.y & 7;
  const int b = blockIdx.z;
  const int chunkId = (b * 16 + (int)blockIdx.y) * NCHK2 + x;
  const unsigned short* Qg = ra ? Qra : Qsa;
  const unsigned short* Kg = ra ? Kra : Ksa;
  const unsigned short* Vg = ra ? SVra : Vsa;
  const int tid = threadIdx.x;
  const int wv = tid >> 6, lane = tid & 63;
  const int r15 = lane & 15, quad = lane >> 4;
  const size_t bh = (size_t)b * S_ * PJ_ + (size_t)h * D_;
  const size_t relStride = (size_t)NTRI * 4096;
  const int it_wave = 2 * a + (wv >> 2);        // wave-uniform
  const int gi = a * 128 + wv * 16 + r15;       // lane's global i-row

  // staging addresses (per-thread constants); 512 threads: one uint4 per tile
  const int kr = tid >> 3, kc0 = (tid & 7) << 3;          // K: row 0..63, col
  const unsigned short* kgp = Kg + bh + (size_t)kr * PJ_ + kc0;
  const unsigned short* vgp = Vg + bh + (size_t)lane * PJ_ + wv * 8;  // V row=lane, d=wv*8..+7
  // sigma^-1: k-slot for this thread's staged V column (j = lane)
  const int kcol = ((lane >> 2) & 3) * 8 + ((lane >> 4) & 1) * 4 + (lane & 3) + (lane >> 5) * 32;

  // Q fragments in registers (layout: row=r15, k=quad*8+j — serves as B-frag)
  const unsigned short* qp = Qg + bh + (size_t)gi * PJ_ + quad * 8;
  const bf16x8 aq0 = *(const bf16x8*)qp;
  const bf16x8 aq1 = *(const bf16x8*)(qp + 32);

  const bf16x8 ones = (bf16x8)(short)0x3F80;   // bf16 1.0 splat (B-frag for l)

  f32x4 o_acc[4];
  f32x4 l_acc = (f32x4){0.f, 0.f, 0.f, 0.f};
  f32x4 accR[8];                               // arp MFMA accumulators (ra only)
#pragma unroll
  for (int n = 0; n < 4; ++n) o_acc[n] = (f32x4){0.f, 0.f, 0.f, 0.f};
#pragma unroll
  for (int rr = 0; rr < 8; ++rr) accR[rr] = (f32x4){0.f, 0.f, 0.f, 0.f};
  // B-frag-sigma rel tile base for this wave's 64-tile row (it_wave)
  const size_t relTileBase = (size_t)(b * 8) * NTRI * 4096
                           + (size_t)(it_wave * (it_wave + 1)) / 2 * 4096
                           + (size_t)(wv & 3) * 1024 + (size_t)lane * 8;

  // one j-tile's QK/softmax/l/arp/PV from buffer slot (KsT, VtT)
  auto TILE = [&](int jtt, const unsigned short (*KsT)[72], const unsigned short (*VtT)[72]) {
    const bool dorel = ra && (jtt <= it_wave);
    const unsigned short* rtBase = RelCF + relTileBase + (size_t)jtt * 4096;
    // ALL 16 rel frag words prefetched up-front (r23): the rr=4..7 pairs
    // now have QK+softmax+PV (~30 MFMAs) between issue and first use.
    uint4 pre[16];
    if (dorel) {
      const unsigned short* rt = rtBase;
#pragma unroll
      for (int q = 0; q < 8; ++q) {
        pre[2 * q]     = *(const uint4*)rt;
        pre[2 * q + 1] = *(const uint4*)(rt + 512);
        rt += relStride;
      }
    }
    // QK^T, SWAPPED operands: lane row i=gi, j = jtt*64 + n*16 + quad*4 + r
    f32x4 s[4];
#pragma unroll
    for (int n = 0; n < 4; ++n) s[n] = (f32x4){0.f, 0.f, 0.f, 0.f};
#pragma unroll
    for (int k0 = 0; k0 < 2; ++k0) {
      const bf16x8 bq = k0 ? aq1 : aq0;
#pragma unroll
      for (int n = 0; n < 4; ++n) {
        const bf16x8 kf = *(const bf16x8*)&KsT[n * 16 + r15][quad * 8 + k0 * 32];
        s[n] = __builtin_amdgcn_mfma_f32_16x16x32_bf16(kf, bq, s[n], 0, 0, 0);
      }
    }
    // fixed-shift softmax: exp(s*0.125-4) = exp2(fma(s, log2e/8, -4log2e))
    if (jtt >= it_wave) {   // diagonal or fully-masked tile
#pragma unroll
      for (int n = 0; n < 4; ++n)
#pragma unroll
        for (int r = 0; r < 4; ++r) {
          const bool ok = (jtt * 64 + n * 16 + quad * 4 + r <= gi);
          s[n][r] = ok ? exp2f(fmaf(s[n][r], 0.180336887f, -5.770780163f)) : 0.f;
        }
    } else {
#pragma unroll
      for (int n = 0; n < 4; ++n)
#pragma unroll
        for (int r = 0; r < 4; ++r)
          s[n][r] = exp2f(fmaf(s[n][r], 0.180336887f, -5.770780163f));
    }
    // packed P->bf16 under sigma
    uint4 w0, w1;
    w0.x = cvtpk_bf16(s[0][0], s[0][1]); w0.y = cvtpk_bf16(s[0][2], s[0][3]);
    w0.z = cvtpk_bf16(s[1][0], s[1][1]); w0.w = cvtpk_bf16(s[1][2], s[1][3]);
    w1.x = cvtpk_bf16(s[2][0], s[2][1]); w1.y = cvtpk_bf16(s[2][2], s[2][3]);
    w1.z = cvtpk_bf16(s[3][0], s[3][1]); w1.w = cvtpk_bf16(s[3][2], s[3][3]);
    const bf16x8 pa0 = u4_to_bf(w0);
    const bf16x8 pa1 = u4_to_bf(w1);
    // l via MFMA against constant ones B-frag
    l_acc = __builtin_amdgcn_mfma_f32_16x16x32_bf16(pa0, ones, l_acc, 0, 0, 0);
    l_acc = __builtin_amdgcn_mfma_f32_16x16x32_bf16(pa1, ones, l_acc, 0, 0, 0);
    // arp MFMAs rr=0..3 (diag of D = arp)
    if (dorel) {
#pragma unroll
      for (int rr = 0; rr < 4; ++rr) {
        accR[rr] = __builtin_amdgcn_mfma_f32_16x16x32_bf16(pa0, u4_to_bf(pre[2 * rr]), accR[rr], 0, 0, 0);
        accR[rr] = __builtin_amdgcn_mfma_f32_16x16x32_bf16(pa1, u4_to_bf(pre[2 * rr + 1]), accR[rr], 0, 0, 0);
      }
    }
    // PV: 8 MFMAs (Vt columns are sigma-permuted)
#pragma unroll
    for (int k0 = 0; k0 < 2; ++k0) {
      const bf16x8 pf = k0 ? pa1 : pa0;
#pragma unroll
      for (int n = 0; n < 4; ++n) {
        const bf16x8 vf = *(const bf16x8*)&VtT[n * 16 + r15][quad * 8 + k0 * 32];
        o_acc[n] = __builtin_amdgcn_mfma_f32_16x16x32_bf16(pf, vf, o_acc[n], 0, 0, 0);
      }
    }
    // arp MFMAs rr=4..7 (frags already in pre[8..15])
    if (dorel) {
#pragma unroll
      for (int rr = 4; rr < 8; ++rr) {
        accR[rr] = __builtin_amdgcn_mfma_f32_16x16x32_bf16(pa0, u4_to_bf(pre[2 * rr]), accR[rr], 0, 0, 0);
        accR[rr] = __builtin_amdgcn_mfma_f32_16x16x32_bf16(pa1, u4_to_bf(pre[2 * rr + 1]), accR[rr], 0, 0, 0);
      }
    }
  };

  // prologue: load round (j0, j0+1), store to buf 0
  uint4 ka0, ka1, va0, va1;
  {
    const size_t jb0 = (size_t)j0 * 64 * PJ_;
    const size_t jb1 = (size_t)(j0 + 1) * 64 * PJ_;
    ka0 = *(const uint4*)(kgp + jb0);
    ka1 = *(const uint4*)(kgp + jb1);
    va0 = *(const uint4*)(vgp + jb0);
    va1 = *(const uint4*)(vgp + jb1);
  }
  int p = 0;
  {
    *(uint4*)&Ks[0][0][kr][kc0] = ka0;
    *(uint4*)&Ks[0][1][kr][kc0] = ka1;
    unsigned short t8[8];
    *(uint4*)t8 = va0;
#pragma unroll
    for (int m = 0; m < 8; ++m) Vt[0][0][wv * 8 + m][kcol] = t8[m];
    *(uint4*)t8 = va1;
#pragma unroll
    for (int m = 0; m < 8; ++m) Vt[0][1][wv * 8 + m][kcol] = t8[m];
  }
  __syncthreads();

  for (int jt = j0; jt < jend; jt += 2) {
    const bool more = (jt + 2 < jend);
    if (more) {   // issue next round's loads (2 tiles of compute to hide)
      const size_t jb0 = (size_t)(jt + 2) * 64 * PJ_;
      const size_t jb1 = (size_t)(jt + 3) * 64 * PJ_;
      ka0 = *(const uint4*)(kgp + jb0);
      ka1 = *(const uint4*)(kgp + jb1);
      va0 = *(const uint4*)(vgp + jb0);
      va1 = *(const uint4*)(vgp + jb1);
    }
    TILE(jt,     Ks[p][0], Vt[p][0]);
    TILE(jt + 1, Ks[p][1], Vt[p][1]);
    if (more) {
      const int q = p ^ 1;
      *(uint4*)&Ks[q][0][kr][kc0] = ka0;
      *(uint4*)&Ks[q][1][kr][kc0] = ka1;
      unsigned short t8[8];
      *(uint4*)t8 = va0;
#pragma unroll
      for (int m = 0; m < 8; ++m) Vt[q][0][wv * 8 + m][kcol] = t8[m];
      *(uint4*)t8 = va1;
#pragma unroll
      for (int m = 0; m < 8; ++m) Vt[q][1][wv * 8 + m][kcol] = t8[m];
      __syncthreads();
      p = q;
    }
  }
  // ---- write partials (chunk: Po 128x64, l 128, arp 128x8) ----
  unsigned short* po = PoP + (size_t)chunkId * 8192;
#pragma unroll
  for (int n = 0; n < 4; ++n)
#pragma unroll
    for (int r = 0; r < 4; ++r)
      po[(wv * 16 + quad * 4 + r) * 64 + n * 16 + r15] = f2bf(o_acc[n][r]);
  if (r15 == 0) {
#pragma unroll
    for (int r = 0; r < 4; ++r)
      lP[(size_t)chunkId * 128 + wv * 16 + quad * 4 + r] = l_acc[r];
  }
  // arp: diagonal lanes (quad == r15>>2) hold the full j-sum in comp r15&3
  if (ra && quad == (r15 >> 2)) {
    const int d3 = r15 & 3;
    float* ap = arpP + (size_t)chunkId * 1024 + (size_t)(wv * 16 + r15) * 8;
#pragma unroll
    for (int rr = 0; rr < 8; ++rr) {
      const f32x4 a4 = accR[rr];
      const float v = (d3 == 0) ? a4[0] : (d3 == 1) ? a4[1] : (d3 == 2) ? a4[2] : a4[3];
      ap[rr] = v;
    }
  }
}

// ---------------------------------------------------------------------------
// Merge split-j partials (pure sums) + wr (f32) epilogue. grid (32, 16, 2).
// Chunks are 128-row i-blocks; tile it -> block a = it>>1, half = it&1.
// ---------------------------------------------------------------------------
__global__ __launch_bounds__(256)
void flash_merge(const unsigned short* __restrict__ PoP, const float* __restrict__ lP,
                 const float* __restrict__ arpP, const float* __restrict__ wrF,
                 unsigned short* __restrict__ Osa, unsigned short* __restrict__ Ora)
{
  const int it = blockIdx.x;
  const int hh = blockIdx.y;
  const int b  = blockIdx.z;
  const bool ra = (hh >= 8);
  const int h = hh & 7;
  const int a  = it >> 1;
  const int half = it & 1;
  const int nc = ((2 * a + 1) >> 3) + 1;
  int cb;
  if (a < 4)       cb = a;
  else if (a < 8)  cb = 4 + 2 * (a - 4);
  else if (a < 12) cb = 12 + 3 * (a - 8);
  else             cb = 24 + 4 * (a - 12);
  const int cid0 = (b * 16 + hh) * NCHK2 + cb;
  const int tid = threadIdx.x;
  const int row = tid >> 2;            // 0..63 within this 64-row half
  const int cg  = tid & 3;
  const int prow = half * 64 + row;    // row within the 128-row chunk

  float L = 0.f;
  for (int c = 0; c < nc; ++c) L += lP[(size_t)(cid0 + c) * 128 + prow];
  const float inv = 1.f / L;

  float o[16];
#pragma unroll
  for (int k = 0; k < 16; ++k) o[k] = 0.f;
  for (int c = 0; c < nc; ++c) {
    const unsigned short* pp = PoP + (size_t)(cid0 + c) * 8192 + prow * 64 + cg * 16;
    unsigned int u[8];
    *(uint4*)u       = *(const uint4*)pp;
    *(uint4*)(u + 4) = *(const uint4*)(pp + 8);
#pragma unroll
    for (int q = 0; q < 8; ++q) {
      o[2 * q]     += __uint_as_float(u[q] << 16);
      o[2 * q + 1] += __uint_as_float(u[q] & 0xffff0000u);
    }
  }
  if (ra) {
    float A[8];
#pragma unroll
    for (int rr = 0; rr < 8; ++rr) A[rr] = 0.f;
    for (int c = 0; c < nc; ++c) {
      const float* ap = arpP + (size_t)(cid0 + c) * 1024 + (size_t)prow * 8;
#pragma unroll
      for (int rr = 0; rr < 8; ++rr) A[rr] += ap[rr];
    }
#pragma unroll
    for (int k = 0; k < 16; ++k) {
      const float* wp = wrF + ((size_t)h * 64 + cg * 16 + k) * 8;
      float ro = 0.f;
#pragma unroll
      for (int rr = 0; rr < 8; ++rr) ro += A[rr] * wp[rr];
      o[k] += ro;
    }
  }
  const size_t bh = (size_t)b * S_ * PJ_ + (size_t)h * D_;
  unsigned short* op = (ra ? Ora : Osa) + bh + (size_t)(it * 64 + row) * PJ_ + cg * 16;
#pragma unroll
  for (int k = 0; k < 16; ++k) op[k] = f2bf(o[k] * inv);
}

// ---------------------------------------------------------------------------
extern "C" void kernel_launch(void* const* d_in, const int* in_sizes, int n_in,
                              void* d_out, int out_size, void* d_ws, size_t ws_size,
                              hipStream_t stream)
{
  (void)in_sizes; (void)n_in; (void)out_size; (void)ws_size;
  const float* x    = (const float*)d_in[0];
  const float* sym  = (const float*)d_in[1];
  const float* fc   = (const float*)d_in[2];
  const float* fs   = (const float*)d_in[3];
  const float* wqsa = (const float*)d_in[4];
  const float* wksa = (const float*)d_in[5];
  const float* wvsa = (const float*)d_in[6];
  const float* wosa = (const float*)d_in[7];
  const float* wqat = (const float*)d_in[8];
  const float* wkat = (const float*)d_in[9];
  const float* wqre = (const float*)d_in[10];
  const float* wkre = (const float*)d_in[11];
  const float* wr   = (const float*)d_in[12];
  const float* wvra = (const float*)d_in[13];
  const float* wora = (const float*)d_in[14];

  unsigned short* wsb = (unsigned short*)d_ws;
  const size_t NX = (size_t)B_ * S_ * DM_;
  const size_t NB = (size_t)B_ * S_ * PJ_;
  const size_t NW = (size_t)PJ_ * DM_;
  const size_t NO = (size_t)PJ_ * PJ_;
  const size_t NR = (size_t)B_ * 8 * NTRI * 4096;
  const size_t NCH = (size_t)B_ * 16 * NCHK2;   // 1280 chunks

  size_t off = 0;
  unsigned short* XB   = wsb + off; off += NX;
  unsigned short* SYB  = wsb + off; off += NX;
  unsigned short* WB[8];
  for (int i = 0; i < 8; ++i) { WB[i] = wsb + off; off += NW; }
  unsigned short* WOSA = wsb + off; off += NO;
  unsigned short* WORA = wsb + off; off += NO;
  unsigned short* Q    = wsb + off; off += NB;
  unsigned short* K    = wsb + off; off += NB;
  unsigned short* V    = wsb + off; off += NB;
  unsigned short* QA   = wsb + off; off += NB;
  unsigned short* KA   = wsb + off; off += NB;
  unsigned short* QR   = wsb + off; off += NB;
  unsigned short* KR   = wsb + off; off += NB;
  unsigned short* SV   = wsb + off; off += NB;
  unsigned short* Asa  = wsb + off; off += NB;
  unsigned short* Ara  = wsb + off; off += NB;
  unsigned short* RelCF = wsb + off; off += NR;
  unsigned short* PoP  = XB;                      // aliases dead XB/SYB/WB[0..3]
  float* lP   = (float*)(wsb + off); off += NCH * 128 * 2;
  float* arpP = (float*)(wsb + off); off += NCH * 1024 * 2;

  CvtJobs cj;
  cj.src[0]  = x;    cj.dst[0]  = XB;    cj.n4[0]  = (int)(NX / 4);
  cj.src[1]  = sym;  cj.dst[1]  = SYB;   cj.n4[1]  = (int)(NX / 4);
  cj.src[2]  = wqsa; cj.dst[2]  = WB[0]; cj.n4[2]  = (int)(NW / 4);
  cj.src[3]  = wksa; cj.dst[3]  = WB[1]; cj.n4[3]  = (int)(NW / 4);
  cj.src[4]  = wvsa; cj.dst[4]  = WB[2]; cj.n4[4]  = (int)(NW / 4);
  cj.src[5]  = wqat; cj.dst[5]  = WB[3]; cj.n4[5]  = (int)(NW / 4);
  cj.src[6]  = wkat; cj.dst[6]  = WB[4]; cj.n4[6]  = (int)(NW / 4);
  cj.src[7]  = wqre; cj.dst[7]  = WB[5]; cj.n4[7]  = (int)(NW / 4);
  cj.src[8]  = wkre; cj.dst[8]  = WB[6]; cj.n4[8]  = (int)(NW / 4);
  cj.src[9]  = wvra; cj.dst[9]  = WB[7]; cj.n4[9]  = (int)(NW / 4);
  cj.src[10] = wosa; cj.dst[10] = WOSA;  cj.n4[10] = (int)(NO / 4);
  cj.src[11] = wora; cj.dst[11] = WORA;  cj.n4[11] = (int)(NO / 4);
  cvt_many<<<dim3(4096, 12), dim3(256), 0, stream>>>(cj);

  proj_tiled<<<dim3(32, 32), dim3(256), 0, stream>>>(XB, SYB, WB[0], Q, SV);
  rel_rope<<<dim3(136, 16), dim3(256), 0, stream>>>(QR, KR, RelCF, Q, K, QA, KA, fc, fs);
  flash_part<<<dim3(NCHK2, 16, B_), dim3(512), 0, stream>>>(
      Q, K, V, QA, KA, SV, RelCF, PoP, lP, arpP);
  flash_merge<<<dim3(NT_, 16, B_), dim3(256), 0, stream>>>(
      PoP, lP, arpP, wr, Asa, Ara);
  out_tiled<<<dim3(32, 16), dim3(256), 0, stream>>>(Asa, Ara, WOSA, WORA, (float*)d_out);
}

// Round 10
// 297.399 us; speedup vs baseline: 1.1887x; 1.0038x over previous
//
#include <hip/hip_runtime.h>

#define B_   2
#define S_   2048
#define H_   8
#define D_   64
#define DM_  1024
#define PJ_  512          // H_*D_ = projection width
#define NT_  32           // S_/64 i-tiles
#define NTRI 528          // NT_*(NT_+1)/2 lower-triangular 64-tiles
#define NCHK2 40          // split-j chunks per (b,hh) over 128-row i-blocks

typedef short bf16x8 __attribute__((ext_vector_type(8)));
typedef float f32x4 __attribute__((ext_vector_type(4)));

__device__ __forceinline__ float bf2f(unsigned int u) {
  return __uint_as_float(u << 16);
}
__device__ __forceinline__ unsigned short f2bf(float f) {
  unsigned int u = __float_as_uint(f);
  u += 0x7fffu + ((u >> 16) & 1u);           // round-to-nearest-even
  return (unsigned short)(u >> 16);
}
// packed f32x2 -> bf16x2 (RNE), gfx950 has no builtin (T12) — inline asm
__device__ __forceinline__ unsigned int cvtpk_bf16(float lo, float hi) {
  unsigned int r;
  asm("v_cvt_pk_bf16_f32 %0, %1, %2" : "=v"(r) : "v"(lo), "v"(hi));
  return r;
}
__device__ __forceinline__ bf16x8 u4_to_bf(uint4 v) {
  union { uint4 a; bf16x8 b; } u; u.a = v; return u.b;
}

// async global->LDS DMA, 16 B/lane; LDS dest = wave-uniform base + lane*16
__device__ __forceinline__ void glds16(const unsigned short* g, unsigned short* l) {
  __builtin_amdgcn_global_load_lds(
      (const __attribute__((address_space(1))) void*)g,
      (__attribute__((address_space(3))) void*)l, 16, 0, 0);
}

// ---------------------------------------------------------------------------
// f32 -> bf16 conversion (12 jobs; wr stays f32 and is read directly).
// ---------------------------------------------------------------------------
struct CvtJobs {
  const float*    src[12];
  unsigned short* dst[12];
  int             n4[12];
};

__global__ __launch_bounds__(256) void cvt_many(CvtJobs J) {
  const int j = blockIdx.y;
  const int i = blockIdx.x * 256 + threadIdx.x;
  if (i >= J.n4[j]) return;
  const float4 v = ((const float4*)J.src[j])[i];
  ushort4 o;
  o.x = f2bf(v.x); o.y = f2bf(v.y); o.z = f2bf(v.z); o.w = f2bf(v.w);
  ((ushort4*)J.dst[j])[i] = o;
}

// ---------------------------------------------------------------------------
// 128x128-tile MFMA GEMM with global_load_lds staging (m97 ladder step).
// ---------------------------------------------------------------------------
__device__ __forceinline__
void gemm128_glds(const unsigned short* __restrict__ A, int m0,
                  const unsigned short* __restrict__ Wb,
                  unsigned short* __restrict__ Cb, int ldc, int KD,
                  unsigned short* As, unsigned short* Bs)
{
  const int tid = threadIdx.x;
  const int wv = tid >> 6, lane = tid & 63;
  const int r15 = lane & 15, quad = lane >> 4;
  const int wm = (wv >> 1) * 64, wn = (wv & 1) * 64;
  f32x4 acc[4][4];
#pragma unroll
  for (int i = 0; i < 4; ++i)
#pragma unroll
    for (int j = 0; j < 4; ++j) acc[i][j] = (f32x4){0.f, 0.f, 0.f, 0.f};

  const int srow = wv * 16 + (lane >> 2);
  const int scol = ((lane & 3) ^ ((lane >> 3) & 3)) * 8;   // xor-swizzled source col
  const unsigned short* gaA0 = A + (size_t)(m0 + srow) * KD + scol;
  const unsigned short* gaA1 = gaA0 + (size_t)64 * KD;
  const unsigned short* gaB0 = Wb + (size_t)srow * KD + scol;
  const unsigned short* gaB1 = gaB0 + (size_t)64 * KD;
  unsigned short* ldsA0 = As + wv * 512;
  unsigned short* ldsA1 = As + 2048 + wv * 512;
  unsigned short* ldsB0 = Bs + wv * 512;
  unsigned short* ldsB1 = Bs + 2048 + wv * 512;
  const int rxor = (r15 >> 1) & 3;                         // read-side xor

  for (int kk = 0; kk < KD; kk += 32) {
    __syncthreads();
    glds16(gaA0 + kk, ldsA0);
    glds16(gaA1 + kk, ldsA1);
    glds16(gaB0 + kk, ldsB0);
    glds16(gaB1 + kk, ldsB1);
    __syncthreads();     // drains vmcnt for the DMA
    bf16x8 af[4], bf[4];
#pragma unroll
    for (int i = 0; i < 4; ++i)
      af[i] = *(const bf16x8*)(As + (wm + i * 16 + r15) * 32 + ((quad ^ rxor) << 3));
#pragma unroll
    for (int j = 0; j < 4; ++j)
      bf[j] = *(const bf16x8*)(Bs + (wn + j * 16 + r15) * 32 + ((quad ^ rxor) << 3));
#pragma unroll
    for (int i = 0; i < 4; ++i)
#pragma unroll
      for (int j = 0; j < 4; ++j)
        acc[i][j] = __builtin_amdgcn_mfma_f32_16x16x32_bf16(af[i], bf[j], acc[i][j], 0, 0, 0);
  }
#pragma unroll
  for (int i = 0; i < 4; ++i)
#pragma unroll
    for (int r = 0; r < 4; ++r) {
      unsigned short* cp = Cb + (size_t)(wm + i * 16 + quad * 4 + r) * ldc + wn + r15;
#pragma unroll
      for (int j = 0; j < 4; ++j) cp[j * 16] = f2bf(acc[i][j][r]);
    }
}

// 8 projection GEMMs in one launch. grid (32, 32)
__global__ __launch_bounds__(256)
void proj_tiled(const unsigned short* __restrict__ XB,
                const unsigned short* __restrict__ SYB,
                const unsigned short* __restrict__ Wcat,
                unsigned short* __restrict__ Qbase,
                unsigned short* __restrict__ SV)
{
  __shared__ unsigned short As[128 * 32];
  __shared__ unsigned short Bs[128 * 32];
  const int m0 = blockIdx.x * 128;
  const int ny = blockIdx.y;
  const size_t NB = (size_t)B_ * S_ * PJ_;
  const unsigned short* A;
  const unsigned short* Wb;
  unsigned short* Cb;
  if (ny < 28) {
    const int n0 = ny * 128;
    A  = XB;
    Wb = Wcat + (size_t)n0 * DM_;
    Cb = Qbase + (size_t)(n0 >> 9) * NB + (size_t)m0 * PJ_ + (n0 & 511);
  } else {
    const int n0 = (ny - 28) * 128;
    A  = SYB;
    Wb = Wcat + (size_t)7 * PJ_ * DM_ + (size_t)n0 * DM_;
    Cb = SV + (size_t)m0 * PJ_ + n0;
  }
  gemm128_glds(A, m0, Wb, Cb, PJ_, DM_, As, Bs);
}

// ---------------------------------------------------------------------------
// Output projections: 128m x 64n tiles (512 blocks). grid (32, 16).
// ---------------------------------------------------------------------------
__global__ __launch_bounds__(256)
void out_tiled(const unsigned short* __restrict__ Asa,
               const unsigned short* __restrict__ Ara,
               const unsigned short* __restrict__ WOSA,
               const unsigned short* __restrict__ WORA,
               float* __restrict__ Out)
{
  __shared__ unsigned short As[128 * 40];
  __shared__ unsigned short Bs[64 * 40];
  const int m0 = blockIdx.x * 128;
  const int ny = blockIdx.y;
  const int n0 = (ny & 7) * 64;
  const unsigned short* A  = (ny < 8) ? Asa : Ara;
  const unsigned short* Wb = ((ny < 8) ? WOSA : WORA) + (size_t)n0 * PJ_;
  float* Cb = Out + (size_t)m0 * DM_ + ((ny < 8) ? 0 : 512) + n0;

  const int tid = threadIdx.x;
  const int wv = tid >> 6, lane = tid & 63;
  const int r15 = lane & 15, quad = lane >> 4;
  const int wm = wv * 32;
  f32x4 acc[2][4];
#pragma unroll
  for (int i = 0; i < 2; ++i)
#pragma unroll
    for (int j = 0; j < 4; ++j) acc[i][j] = (f32x4){0.f, 0.f, 0.f, 0.f};

  const int arow = tid >> 1, ac = (tid & 1) * 16;
  const int brow = tid >> 2, bc = (tid & 3) * 8;
  const unsigned short* ga = A + (size_t)(m0 + arow) * PJ_ + ac;
  const unsigned short* gb = Wb + (size_t)brow * PJ_ + bc;
  unsigned short* la = As + arow * 40 + ac;
  unsigned short* lb = Bs + brow * 40 + bc;

  for (int kk = 0; kk < PJ_; kk += 32) {
    __syncthreads();
    const uint4 a0 = *(const uint4*)(ga + kk);
    const uint4 a1 = *(const uint4*)(ga + kk + 8);
    const uint4 b0 = *(const uint4*)(gb + kk);
    *(uint4*)la       = a0;
    *(uint4*)(la + 8) = a1;
    *(uint4*)lb       = b0;
    __syncthreads();
    bf16x8 af[2], bf[4];
#pragma unroll
    for (int i = 0; i < 2; ++i)
      af[i] = *(const bf16x8*)(As + (wm + i * 16 + r15) * 40 + quad * 8);
#pragma unroll
    for (int j = 0; j < 4; ++j)
      bf[j] = *(const bf16x8*)(Bs + (j * 16 + r15) * 40 + quad * 8);
#pragma unroll
    for (int i = 0; i < 2; ++i)
#pragma unroll
      for (int j = 0; j < 4; ++j)
        acc[i][j] = __builtin_amdgcn_mfma_f32_16x16x32_bf16(af[i], bf[j], acc[i][j], 0, 0, 0);
  }
#pragma unroll
  for (int i = 0; i < 2; ++i)
#pragma unroll
    for (int r = 0; r < 4; ++r) {
      float* cp = Cb + (size_t)(wm + i * 16 + quad * 4 + r) * DM_ + r15;
#pragma unroll
      for (int j = 0; j < 4; ++j) cp[j * 16] = acc[i][j][r];
    }
}

// ---------------------------------------------------------------------------
// rel materialization (tri-128 LDS GEMM), FUSED with vectorized RoPE.
// Tiles stored in B-frag-sigma order so flash_part feeds them DIRECTLY into
// MFMA as the second operand (arp-as-MFMA):
//   flat tile index = sub*1024 + k0*512 + lane*8 + jj  holds
//   rel[i' = sub*16 + (lane&15)][j = ((k0<<1)|(jj>>2))*16 + (lane>>4)*4 + (jj&3)]
// grid (136, 16).
// ---------------------------------------------------------------------------
__global__ __launch_bounds__(256)
void rel_rope(const unsigned short* __restrict__ QRg, const unsigned short* __restrict__ KRg,
              unsigned short* __restrict__ RelCF,
              unsigned short* __restrict__ Qp, unsigned short* __restrict__ Kp,
              unsigned short* __restrict__ QAp, unsigned short* __restrict__ KAp,
              const float* __restrict__ fcp, const float* __restrict__ fsp)
{
  __shared__ unsigned short As[128 * 72];
  __shared__ unsigned short Bs[128 * 72];
  const int t = blockIdx.x;
  int I = 0;
  while ((I + 1) * (I + 2) / 2 <= t) ++I;
  const int J = t - I * (I + 1) / 2;
  const int rr = blockIdx.y & 7, b = blockIdx.y >> 3;
  const int tid = threadIdx.x;
  const int wv = tid >> 6, lane = tid & 63;
  const int r15 = lane & 15, quad = lane >> 4;

  const int srow = tid >> 1, c32 = (tid & 1) * 32;
  const unsigned short* ga = QRg + (size_t)(b * S_ + I * 128 + srow) * PJ_ + rr * 64 + c32;
  const unsigned short* gb = KRg + (size_t)(b * S_ + J * 128 + srow) * PJ_ + rr * 64 + c32;
  unsigned short* la = As + srow * 72 + c32;
  unsigned short* lb = Bs + srow * 72 + c32;
#pragma unroll
  for (int q = 0; q < 4; ++q) {
    *(uint4*)(la + q * 8) = *(const uint4*)(ga + q * 8);
    *(uint4*)(lb + q * 8) = *(const uint4*)(gb + q * 8);
  }
  __syncthreads();

  const int wm = (wv >> 1) * 64, wn = (wv & 1) * 64;
  const int it64 = 2 * I + (wv >> 1), jt64 = 2 * J + (wv & 1);
  if (jt64 <= it64) {
    f32x4 acc[4][4];           // acc[a][b]: a = j-16-block, b = i-16-block
#pragma unroll
    for (int a = 0; a < 4; ++a)
#pragma unroll
      for (int bq = 0; bq < 4; ++bq) acc[a][bq] = (f32x4){0.f, 0.f, 0.f, 0.f};
#pragma unroll
    for (int k0 = 0; k0 < 2; ++k0) {
      bf16x8 af[4], bf[4];
#pragma unroll
      for (int i = 0; i < 4; ++i)
        af[i] = *(const bf16x8*)(As + (wm + i * 16 + r15) * 72 + quad * 8 + k0 * 32);
#pragma unroll
      for (int j = 0; j < 4; ++j)
        bf[j] = *(const bf16x8*)(Bs + (wn + j * 16 + r15) * 72 + quad * 8 + k0 * 32);
#pragma unroll
      for (int a = 0; a < 4; ++a)
#pragma unroll
        for (int bq = 0; bq < 4; ++bq)
          acc[a][bq] = __builtin_amdgcn_mfma_f32_16x16x32_bf16(bf[a], af[bq], acc[a][bq], 0, 0, 0);
    }
    unsigned short* out = RelCF + ((size_t)(b * 8 + rr) * NTRI + (size_t)it64 * (it64 + 1) / 2 + jt64) * 4096;
#pragma unroll
    for (int bq = 0; bq < 4; ++bq) {
      unsigned short tmp[16];
#pragma unroll
      for (int a = 0; a < 4; ++a)
#pragma unroll
        for (int r = 0; r < 4; ++r)
          tmp[a * 4 + r] = f2bf(acc[a][bq][r] * 0.125f);
      unsigned short* op = out + (size_t)bq * 1024 + (size_t)lane * 8;   // k0=0 half
      *(uint4*)op         = *(const uint4*)tmp;
      *(uint4*)(op + 512) = *(const uint4*)(tmp + 8);                    // k0=1 half
    }
  }

  // ---- fused RoPE (all threads): 2 uint4 slices of {Q,K,QA,KA} each ----
  // per-tensor uint4 count = NB/8 = 262144 = 2^18; total = 4*2^18 = 1048576.
  const int bid = (int)blockIdx.y * 136 + (int)blockIdx.x;
  const int gt = bid * 256 + tid;
#pragma unroll
  for (int k = 0; k < 2; ++k) {
    const int i = gt * 2 + k;
    if (i >= 4 * 262144) continue;
    const int tn = i >> 18;
    const int r2 = i & 262143;
    unsigned short* P = (tn == 0) ? Qp : (tn == 1) ? Kp : (tn == 2) ? QAp : KAp;
    const int b2 = r2 >> 17;                  // 131072 uint4 per batch
    const int s2 = (r2 >> 6) & 2047;          // 64 uint4 per 512-wide row
    const int c8 = (r2 & 63) * 8;             // column offset (elements)
    const int ci0 = (c8 & 63) >> 1;           // first rotary index of 4 pairs
    const size_t off2 = ((size_t)(b2 * S_ + s2)) * PJ_ + c8;
    uint4 v = *(const uint4*)(P + off2);
    unsigned int u[4] = {v.x, v.y, v.z, v.w};
    unsigned int o[4];
#pragma unroll
    for (int q = 0; q < 4; ++q) {
      const float xr = __uint_as_float(u[q] << 16);
      const float xi = __uint_as_float(u[q] & 0xffff0000u);
      const float cs = fcp[s2 * 32 + ci0 + q];
      const float sn = fsp[s2 * 32 + ci0 + q];
      const unsigned short lo = f2bf(xr * cs - xi * sn);
      const unsigned short hi = f2bf(xr * sn + xi * cs);
      o[q] = (unsigned int)lo | ((unsigned int)hi << 16);
    }
    uint4 ov; ov.x = o[0]; ov.y = o[1]; ov.z = o[2]; ov.w = o[3];
    *(uint4*)(P + off2) = ov;
  }
}

// ---------------------------------------------------------------------------
// Split-j flash partial pass — r24: r23 structure + T5 s_setprio around the
// MFMA-dense spans only (QK; l+arp0..3; PV+arp4..7), prio 0 across the
// softmax/pack VALU stretches.  Mechanism: 2 independent blocks/CU at
// uncorrelated round phases -> the scheduler can favor whichever resident
// wave is issuing MFMAs (m191: +4-7% attn; m190 null only for lock-step).
// Zero VGPR/LDS impact; isolated test (r20's setprio was confounded).
// Session A/B ledger (do not revisit):
//  * launch_bounds min-waves arg -> 64-VGPR clamp + ~600 MB spill (r1/r18).
//  * K-direct-from-global -> uncovered QK-critical loads, 92->143 (r20).
//  * masked-tile early-return / serialized rel pipeline -> 92->101 (r21).
//  * all-16 rel prefetch up-front -> 93.3->90.3 (r23, keep).
// grid (40, 16, 2). Partials per chunk: Po bf16 128x64, l f32 128, arp f32 128x8.
// ---------------------------------------------------------------------------
__global__ __launch_bounds__(512)
void flash_part(const unsigned short* __restrict__ Qsa, const unsigned short* __restrict__ Ksa,
                const unsigned short* __restrict__ Vsa,
                const unsigned short* __restrict__ Qra, const unsigned short* __restrict__ Kra,
                const unsigned short* __restrict__ SVra,
                const unsigned short* __restrict__ RelCF,
                unsigned short* __restrict__ PoP, float* __restrict__ lP,
                float* __restrict__ arpP)
{
  __shared__ unsigned short Ks[2][2][64][72];
  __shared__ unsigned short Vt[2][2][64][72];   // [buf][tile][d][kslot]
  const int x = NCHK2 - 1 - (int)blockIdx.x;    // big chunks dispatch first
  int a, c;
  if (x < 4)       { a = x;                 c = 0; }
  else if (x < 12) { a = 4 + ((x - 4) >> 1);  c = (x - 4) & 1; }
  else if (x < 24) { a = 8 + (x - 12) / 3;    c = (x - 12) % 3; }
  else             { a = 12 + ((x - 24) >> 2); c = (x - 24) & 3; }
  const int j0 = c * 8;
  const int jendF = 2 * a + 2;
  const int jend = (j0 + 8 < jendF) ? (j0 + 8) : jendF;   // always even
  const bool ra = (blockIdx.y >= 8);
  const int h = blockIdx.y & 7;
  const int b = blockIdx.z;
  const int chunkId = (b * 16 + (int)blockIdx.y) * NCHK2 + x;
  const unsigned short* Qg = ra ? Qra : Qsa;
  const unsigned short* Kg = ra ? Kra : Ksa;
  const unsigned short* Vg = ra ? SVra : Vsa;
  const int tid = threadIdx.x;
  const int wv = tid >> 6, lane = tid & 63;
  const int r15 = lane & 15, quad = lane >> 4;
  const size_t bh = (size_t)b * S_ * PJ_ + (size_t)h * D_;
  const size_t relStride = (size_t)NTRI * 4096;
  const int it_wave = 2 * a + (wv >> 2);        // wave-uniform
  const int gi = a * 128 + wv * 16 + r15;       // lane's global i-row

  // staging addresses (per-thread constants); 512 threads: one uint4 per tile
  const int kr = tid >> 3, kc0 = (tid & 7) << 3;          // K: row 0..63, col
  const unsigned short* kgp = Kg + bh + (size_t)kr * PJ_ + kc0;
  const unsigned short* vgp = Vg + bh + (size_t)lane * PJ_ + wv * 8;  // V row=lane, d=wv*8..+7
  // sigma^-1: k-slot for this thread's staged V column (j = lane)
  const int kcol = ((lane >> 2) & 3) * 8 + ((lane >> 4) & 1) * 4 + (lane & 3) + (lane >> 5) * 32;

  // Q fragments in registers (layout: row=r15, k=quad*8+j — serves as B-frag)
  const unsigned short* qp = Qg + bh + (size_t)gi * PJ_ + quad * 8;
  const bf16x8 aq0 = *(const bf16x8*)qp;
  const bf16x8 aq1 = *(const bf16x8*)(qp + 32);

  const bf16x8 ones = (bf16x8)(short)0x3F80;   // bf16 1.0 splat (B-frag for l)

  f32x4 o_acc[4];
  f32x4 l_acc = (f32x4){0.f, 0.f, 0.f, 0.f};
  f32x4 accR[8];                               // arp MFMA accumulators (ra only)
#pragma unroll
  for (int n = 0; n < 4; ++n) o_acc[n] = (f32x4){0.f, 0.f, 0.f, 0.f};
#pragma unroll
  for (int rr = 0; rr < 8; ++rr) accR[rr] = (f32x4){0.f, 0.f, 0.f, 0.f};
  // B-frag-sigma rel tile base for this wave's 64-tile row (it_wave)
  const size_t relTileBase = (size_t)(b * 8) * NTRI * 4096
                           + (size_t)(it_wave * (it_wave + 1)) / 2 * 4096
                           + (size_t)(wv & 3) * 1024 + (size_t)lane * 8;

  // one j-tile's QK/softmax/l/arp/PV from buffer slot (KsT, VtT)
  auto TILE = [&](int jtt, const unsigned short (*KsT)[72], const unsigned short (*VtT)[72]) {
    const bool dorel = ra && (jtt <= it_wave);
    const unsigned short* rtBase = RelCF + relTileBase + (size_t)jtt * 4096;
    // ALL 16 rel frag words prefetched up-front (r23): the rr=4..7 pairs
    // have QK+softmax+PV (~30 MFMAs) between issue and first use.
    uint4 pre[16];
    if (dorel) {
      const unsigned short* rt = rtBase;
#pragma unroll
      for (int q = 0; q < 8; ++q) {
        pre[2 * q]     = *(const uint4*)rt;
        pre[2 * q + 1] = *(const uint4*)(rt + 512);
        rt += relStride;
      }
    }
    // QK^T, SWAPPED operands: lane row i=gi, j = jtt*64 + n*16 + quad*4 + r
    f32x4 s[4];
#pragma unroll
    for (int n = 0; n < 4; ++n) s[n] = (f32x4){0.f, 0.f, 0.f, 0.f};
    __builtin_amdgcn_s_setprio(1);
#pragma unroll
    for (int k0 = 0; k0 < 2; ++k0) {
      const bf16x8 bq = k0 ? aq1 : aq0;
#pragma unroll
      for (int n = 0; n < 4; ++n) {
        const bf16x8 kf = *(const bf16x8*)&KsT[n * 16 + r15][quad * 8 + k0 * 32];
        s[n] = __builtin_amdgcn_mfma_f32_16x16x32_bf16(kf, bq, s[n], 0, 0, 0);
      }
    }
    __builtin_amdgcn_s_setprio(0);
    // fixed-shift softmax: exp(s*0.125-4) = exp2(fma(s, log2e/8, -4log2e))
    if (jtt >= it_wave) {   // diagonal or fully-masked tile
#pragma unroll
      for (int n = 0; n < 4; ++n)
#pragma unroll
        for (int r = 0; r < 4; ++r) {
          const bool ok = (jtt * 64 + n * 16 + quad * 4 + r <= gi);
          s[n][r] = ok ? exp2f(fmaf(s[n][r], 0.180336887f, -5.770780163f)) : 0.f;
        }
    } else {
#pragma unroll
      for (int n = 0; n < 4; ++n)
#pragma unroll
        for (int r = 0; r < 4; ++r)
          s[n][r] = exp2f(fmaf(s[n][r], 0.180336887f, -5.770780163f));
    }
    // packed P->bf16 under sigma
    uint4 w0, w1;
    w0.x = cvtpk_bf16(s[0][0], s[0][1]); w0.y = cvtpk_bf16(s[0][2], s[0][3]);
    w0.z = cvtpk_bf16(s[1][0], s[1][1]); w0.w = cvtpk_bf16(s[1][2], s[1][3]);
    w1.x = cvtpk_bf16(s[2][0], s[2][1]); w1.y = cvtpk_bf16(s[2][2], s[2][3]);
    w1.z = cvtpk_bf16(s[3][0], s[3][1]); w1.w = cvtpk_bf16(s[3][2], s[3][3]);
    const bf16x8 pa0 = u4_to_bf(w0);
    const bf16x8 pa1 = u4_to_bf(w1);
    // l via MFMA against constant ones B-frag + arp rr=0..3 (MFMA span)
    __builtin_amdgcn_s_setprio(1);
    l_acc = __builtin_amdgcn_mfma_f32_16x16x32_bf16(pa0, ones, l_acc, 0, 0, 0);
    l_acc = __builtin_amdgcn_mfma_f32_16x16x32_bf16(pa1, ones, l_acc, 0, 0, 0);
    if (dorel) {
#pragma unroll
      for (int rr = 0; rr < 4; ++rr) {
        accR[rr] = __builtin_amdgcn_mfma_f32_16x16x32_bf16(pa0, u4_to_bf(pre[2 * rr]), accR[rr], 0, 0, 0);
        accR[rr] = __builtin_amdgcn_mfma_f32_16x16x32_bf16(pa1, u4_to_bf(pre[2 * rr + 1]), accR[rr], 0, 0, 0);
      }
    }
    // PV: 8 MFMAs (Vt columns are sigma-permuted) + arp rr=4..7
#pragma unroll
    for (int k0 = 0; k0 < 2; ++k0) {
      const bf16x8 pf = k0 ? pa1 : pa0;
#pragma unroll
      for (int n = 0; n < 4; ++n) {
        const bf16x8 vf = *(const bf16x8*)&VtT[n * 16 + r15][quad * 8 + k0 * 32];
        o_acc[n] = __builtin_amdgcn_mfma_f32_16x16x32_bf16(pf, vf, o_acc[n], 0, 0, 0);
      }
    }
    if (dorel) {
#pragma unroll
      for (int rr = 4; rr < 8; ++rr) {
        accR[rr] = __builtin_amdgcn_mfma_f32_16x16x32_bf16(pa0, u4_to_bf(pre[2 * rr]), accR[rr], 0, 0, 0);
        accR[rr] = __builtin_amdgcn_mfma_f32_16x16x32_bf16(pa1, u4_to_bf(pre[2 * rr + 1]), accR[rr], 0, 0, 0);
      }
    }
    __builtin_amdgcn_s_setprio(0);
  };

  // prologue: load round (j0, j0+1), store to buf 0
  uint4 ka0, ka1, va0, va1;
  {
    const size_t jb0 = (size_t)j0 * 64 * PJ_;
    const size_t jb1 = (size_t)(j0 + 1) * 64 * PJ_;
    ka0 = *(const uint4*)(kgp + jb0);
    ka1 = *(const uint4*)(kgp + jb1);
    va0 = *(const uint4*)(vgp + jb0);
    va1 = *(const uint4*)(vgp + jb1);
  }
  int p = 0;
  {
    *(uint4*)&Ks[0][0][kr][kc0] = ka0;
    *(uint4*)&Ks[0][1][kr][kc0] = ka1;
    unsigned short t8[8];
    *(uint4*)t8 = va0;
#pragma unroll
    for (int m = 0; m < 8; ++m) Vt[0][0][wv * 8 + m][kcol] = t8[m];
    *(uint4*)t8 = va1;
#pragma unroll
    for (int m = 0; m < 8; ++m) Vt[0][1][wv * 8 + m][kcol] = t8[m];
  }
  __syncthreads();

  for (int jt = j0; jt < jend; jt += 2) {
    const bool more = (jt + 2 < jend);
    if (more) {   // issue next round's loads (2 tiles of compute to hide)
      const size_t jb0 = (size_t)(jt + 2) * 64 * PJ_;
      const size_t jb1 = (size_t)(jt + 3) * 64 * PJ_;
      ka0 = *(const uint4*)(kgp + jb0);
      ka1 = *(const uint4*)(kgp + jb1);
      va0 = *(const uint4*)(vgp + jb0);
      va1 = *(const uint4*)(vgp + jb1);
    }
    TILE(jt,     Ks[p][0], Vt[p][0]);
    TILE(jt + 1, Ks[p][1], Vt[p][1]);
    if (more) {
      const int q = p ^ 1;
      *(uint4*)&Ks[q][0][kr][kc0] = ka0;
      *(uint4*)&Ks[q][1][kr][kc0] = ka1;
      unsigned short t8[8];
      *(uint4*)t8 = va0;
#pragma unroll
      for (int m = 0; m < 8; ++m) Vt[q][0][wv * 8 + m][kcol] = t8[m];
      *(uint4*)t8 = va1;
#pragma unroll
      for (int m = 0; m < 8; ++m) Vt[q][1][wv * 8 + m][kcol] = t8[m];
      __syncthreads();
      p = q;
    }
  }
  // ---- write partials (chunk: Po 128x64, l 128, arp 128x8) ----
  unsigned short* po = PoP + (size_t)chunkId * 8192;
#pragma unroll
  for (int n = 0; n < 4; ++n)
#pragma unroll
    for (int r = 0; r < 4; ++r)
      po[(wv * 16 + quad * 4 + r) * 64 + n * 16 + r15] = f2bf(o_acc[n][r]);
  if (r15 == 0) {
#pragma unroll
    for (int r = 0; r < 4; ++r)
      lP[(size_t)chunkId * 128 + wv * 16 + quad * 4 + r] = l_acc[r];
  }
  // arp: diagonal lanes (quad == r15>>2) hold the full j-sum in comp r15&3
  if (ra && quad == (r15 >> 2)) {
    const int d3 = r15 & 3;
    float* ap = arpP + (size_t)chunkId * 1024 + (size_t)(wv * 16 + r15) * 8;
#pragma unroll
    for (int rr = 0; rr < 8; ++rr) {
      const f32x4 a4 = accR[rr];
      const float v = (d3 == 0) ? a4[0] : (d3 == 1) ? a4[1] : (d3 == 2) ? a4[2] : a4[3];
      ap[rr] = v;
    }
  }
}

// ---------------------------------------------------------------------------
// Merge split-j partials (pure sums) + wr (f32) epilogue. grid (32, 16, 2).
// Chunks are 128-row i-blocks; tile it -> block a = it>>1, half = it&1.
// ---------------------------------------------------------------------------
__global__ __launch_bounds__(256)
void flash_merge(const unsigned short* __restrict__ PoP, const float* __restrict__ lP,
                 const float* __restrict__ arpP, const float* __restrict__ wrF,
                 unsigned short* __restrict__ Osa, unsigned short* __restrict__ Ora)
{
  const int it = blockIdx.x;
  const int hh = blockIdx.y;
  const int b  = blockIdx.z;
  const bool ra = (hh >= 8);
  const int h = hh & 7;
  const int a  = it >> 1;
  const int half = it & 1;
  const int nc = ((2 * a + 1) >> 3) + 1;
  int cb;
  if (a < 4)       cb = a;
  else if (a < 8)  cb = 4 + 2 * (a - 4);
  else if (a < 12) cb = 12 + 3 * (a - 8);
  else             cb = 24 + 4 * (a - 12);
  const int cid0 = (b * 16 + hh) * NCHK2 + cb;
  const int tid = threadIdx.x;
  const int row = tid >> 2;            // 0..63 within this 64-row half
  const int cg  = tid & 3;
  const int prow = half * 64 + row;    // row within the 128-row chunk

  float L = 0.f;
  for (int c = 0; c < nc; ++c) L += lP[(size_t)(cid0 + c) * 128 + prow];
  const float inv = 1.f / L;

  float o[16];
#pragma unroll
  for (int k = 0; k < 16; ++k) o[k] = 0.f;
  for (int c = 0; c < nc; ++c) {
    const unsigned short* pp = PoP + (size_t)(cid0 + c) * 8192 + prow * 64 + cg * 16;
    unsigned int u[8];
    *(uint4*)u       = *(const uint4*)pp;
    *(uint4*)(u + 4) = *(const uint4*)(pp + 8);
#pragma unroll
    for (int q = 0; q < 8; ++q) {
      o[2 * q]     += __uint_as_float(u[q] << 16);
      o[2 * q + 1] += __uint_as_float(u[q] & 0xffff0000u);
    }
  }
  if (ra) {
    float A[8];
#pragma unroll
    for (int rr = 0; rr < 8; ++rr) A[rr] = 0.f;
    for (int c = 0; c < nc; ++c) {
      const float* ap = arpP + (size_t)(cid0 + c) * 1024 + (size_t)prow * 8;
#pragma unroll
      for (int rr = 0; rr < 8; ++rr) A[rr] += ap[rr];
    }
#pragma unroll
    for (int k = 0; k < 16; ++k) {
      const float* wp = wrF + ((size_t)h * 64 + cg * 16 + k) * 8;
      float ro = 0.f;
#pragma unroll
      for (int rr = 0; rr < 8; ++rr) ro += A[rr] * wp[rr];
      o[k] += ro;
    }
  }
  const size_t bh = (size_t)b * S_ * PJ_ + (size_t)h * D_;
  unsigned short* op = (ra ? Ora : Osa) + bh + (size_t)(it * 64 + row) * PJ_ + cg * 16;
#pragma unroll
  for (int k = 0; k < 16; ++k) op[k] = f2bf(o[k] * inv);
}

// ---------------------------------------------------------------------------
extern "C" void kernel_launch(void* const* d_in, const int* in_sizes, int n_in,
                              void* d_out, int out_size, void* d_ws, size_t ws_size,
                              hipStream_t stream)
{
  (void)in_sizes; (void)n_in; (void)out_size; (void)ws_size;
  const float* x    = (const float*)d_in[0];
  const float* sym  = (const float*)d_in[1];
  const float* fc   = (const float*)d_in[2];
  const float* fs   = (const float*)d_in[3];
  const float* wqsa = (const float*)d_in[4];
  const float* wksa = (const float*)d_in[5];
  const float* wvsa = (const float*)d_in[6];
  const float* wosa = (const float*)d_in[7];
  const float* wqat = (const float*)d_in[8];
  const float* wkat = (const float*)d_in[9];
  const float* wqre = (const float*)d_in[10];
  const float* wkre = (const float*)d_in[11];
  const float* wr   = (const float*)d_in[12];
  const float* wvra = (const float*)d_in[13];
  const float* wora = (const float*)d_in[14];

  unsigned short* wsb = (unsigned short*)d_ws;
  const size_t NX = (size_t)B_ * S_ * DM_;
  const size_t NB = (size_t)B_ * S_ * PJ_;
  const size_t NW = (size_t)PJ_ * DM_;
  const size_t NO = (size_t)PJ_ * PJ_;
  const size_t NR = (size_t)B_ * 8 * NTRI * 4096;
  const size_t NCH = (size_t)B_ * 16 * NCHK2;   // 1280 chunks

  size_t off = 0;
  unsigned short* XB   = wsb + off; off += NX;
  unsigned short* SYB  = wsb + off; off += NX;
  unsigned short* WB[8];
  for (int i = 0; i < 8; ++i) { WB[i] = wsb + off; off += NW; }
  unsigned short* WOSA = wsb + off; off += NO;
  unsigned short* WORA = wsb + off; off += NO;
  unsigned short* Q    = wsb + off; off += NB;
  unsigned short* K    = wsb + off; off += NB;
  unsigned short* V    = wsb + off; off += NB;
  unsigned short* QA   = wsb + off; off += NB;
  unsigned short* KA   = wsb + off; off += NB;
  unsigned short* QR   = wsb + off; off += NB;
  unsigned short* KR   = wsb + off; off += NB;
  unsigned short* SV   = wsb + off; off += NB;
  unsigned short* Asa  = wsb + off; off += NB;
  unsigned short* Ara  = wsb + off; off += NB;
  unsigned short* RelCF = wsb + off; off += NR;
  unsigned short* PoP  = XB;                      // aliases dead XB/SYB/WB[0..3]
  float* lP   = (float*)(wsb + off); off += NCH * 128 * 2;
  float* arpP = (float*)(wsb + off); off += NCH * 1024 * 2;

  CvtJobs cj;
  cj.src[0]  = x;    cj.dst[0]  = XB;    cj.n4[0]  = (int)(NX / 4);
  cj.src[1]  = sym;  cj.dst[1]  = SYB;   cj.n4[1]  = (int)(NX / 4);
  cj.src[2]  = wqsa; cj.dst[2]  = WB[0]; cj.n4[2]  = (int)(NW / 4);
  cj.src[3]  = wksa; cj.dst[3]  = WB[1]; cj.n4[3]  = (int)(NW / 4);
  cj.src[4]  = wvsa; cj.dst[4]  = WB[2]; cj.n4[4]  = (int)(NW / 4);
  cj.src[5]  = wqat; cj.dst[5]  = WB[3]; cj.n4[5]  = (int)(NW / 4);
  cj.src[6]  = wkat; cj.dst[6]  = WB[4]; cj.n4[6]  = (int)(NW / 4);
  cj.src[7]  = wqre; cj.dst[7]  = WB[5]; cj.n4[7]  = (int)(NW / 4);
  cj.src[8]  = wkre; cj.dst[8]  = WB[6]; cj.n4[8]  = (int)(NW / 4);
  cj.src[9]  = wvra; cj.dst[9]  = WB[7]; cj.n4[9]  = (int)(NW / 4);
  cj.src[10] = wosa; cj.dst[10] = WOSA;  cj.n4[10] = (int)(NO / 4);
  cj.src[11] = wora; cj.dst[11] = WORA;  cj.n4[11] = (int)(NO / 4);
  cvt_many<<<dim3(4096, 12), dim3(256), 0, stream>>>(cj);

  proj_tiled<<<dim3(32, 32), dim3(256), 0, stream>>>(XB, SYB, WB[0], Q, SV);
  rel_rope<<<dim3(136, 16), dim3(256), 0, stream>>>(QR, KR, RelCF, Q, K, QA, KA, fc, fs);
  flash_part<<<dim3(NCHK2, 16, B_), dim3(512), 0, stream>>>(
      Q, K, V, QA, KA, SV, RelCF, PoP, lP, arpP);
  flash_merge<<<dim3(NT_, 16, B_), dim3(256), 0, stream>>>(
      PoP, lP, arpP, wr, Asa, Ara);
  out_tiled<<<dim3(32, 16), dim3(256), 0, stream>>>(Asa, Ara, WOSA, WORA, (float*)d_out);
}